// Round 2
// baseline (3488.870 us; speedup 1.0000x reference)
//
#include <hip/hip_runtime.h>
#include <math.h>

#define HMOD 128
#define DIN 256
#define NHEADS 4
#define HD 64
#define DSTATE 16
#define NCH 64
#define CONVD 288
#define DPROJ 548
#define LAT 64
#define LSEQ 4096

__device__ __forceinline__ float sigm(float x){ return 1.0f/(1.0f+expf(-x)); }
__device__ __forceinline__ float softplusf(float x){ return (x>20.0f)? x : log1pf(expf(x)); }
__device__ __forceinline__ float geluf(float x){ return 0.5f*x*(1.0f+erff(x*0.70710678118654752440f)); }

// ---------------- embedding (writes fwd and reversed bwd input), group-local ----------------
__global__ __launch_bounds__(256) void embed_kernel(const float* __restrict__ expr,
    const float* __restrict__ ew, const float* __restrict__ eb,
    float* __restrict__ actA, float* __restrict__ actB)
{
  int gid = blockIdx.x*256 + threadIdx.x;    // MG*128
  int m = gid >> 7, hh = gid & 127;          // m: local token
  int bl = m >> 12, g = m & 4095;
  float v = expr[m]*ew[hh] + eb[hh];
  actA[gid] = v;
  actB[(size_t)(((bl<<12) | (4095-g))<<7) + hh] = v;
}

// ---------------- in_proj GEMM: (MG,128)@(548,128)^T with routed epilogue ----------------
__global__ __launch_bounds__(256) void gemm_in_kernel(
  const float* __restrict__ A, const float* __restrict__ W,
  const float* __restrict__ dtb,
  float* __restrict__ zbuf, float* __restrict__ xraw, float* __restrict__ dtsp)
{
  __shared__ float As[16][68];
  __shared__ float Ws[16][68];
  const int tid = threadIdx.x;
  const int m0 = blockIdx.x<<6, n0 = blockIdx.y<<6;
  const int ty = tid>>4, tx = tid&15;
  float acc[4][4] = {};
  for (int kt=0; kt<128; kt+=16){
    #pragma unroll
    for (int i=0;i<4;i++){
      int e = tid + (i<<8); int r = e>>4, cc = e&15;
      As[cc][r] = A[(size_t)(m0+r)*128 + kt+cc];
      int n = n0 + r;
      Ws[cc][r] = (n < DPROJ) ? W[(size_t)n*128 + kt+cc] : 0.f;
    }
    __syncthreads();
    #pragma unroll
    for (int kk=0;kk<16;kk++){
      float4 a4 = *(const float4*)&As[kk][ty<<2];
      float4 w4 = *(const float4*)&Ws[kk][tx<<2];
      float av[4] = {a4.x,a4.y,a4.z,a4.w};
      float wv[4] = {w4.x,w4.y,w4.z,w4.w};
      #pragma unroll
      for (int a=0;a<4;a++)
        #pragma unroll
        for (int bb=0;bb<4;bb++) acc[a][bb] = fmaf(av[a], wv[bb], acc[a][bb]);
    }
    __syncthreads();
  }
  #pragma unroll
  for (int a=0;a<4;a++){
    int m = m0 + (ty<<2) + a;
    #pragma unroll
    for (int bb=0;bb<4;bb++){
      int n = n0 + (tx<<2) + bb;
      if (n >= DPROJ) continue;
      float v = acc[a][bb];
      if (n < DIN)              zbuf[(size_t)m*DIN + n] = v;
      else if (n < DIN+CONVD)   xraw[(size_t)m*CONVD + (n-DIN)] = v;
      else                      dtsp[(size_t)m*NHEADS + (n-DIN-CONVD)] = softplusf(v + dtb[n-DIN-CONVD]);
    }
  }
}

// ---------------- generic GEMM: (M,K)@(N,K)^T, optional bias / gelu ----------------
template<int ACT>
__global__ __launch_bounds__(256) void gemm_plain(
  const float* __restrict__ A, int lda,
  const float* __restrict__ W,
  const float* __restrict__ bias,
  float* __restrict__ C, int ldc,
  int N, int K)
{
  __shared__ float As[16][68];
  __shared__ float Ws[16][68];
  const int tid = threadIdx.x;
  const int m0 = blockIdx.x<<6, n0 = blockIdx.y<<6;
  const int ty = tid>>4, tx = tid&15;
  float acc[4][4] = {};
  for (int kt=0; kt<K; kt+=16){
    #pragma unroll
    for (int i=0;i<4;i++){
      int e = tid + (i<<8); int r = e>>4, cc = e&15;
      As[cc][r] = A[(size_t)(m0+r)*lda + kt+cc];
      int n = n0 + r;
      Ws[cc][r] = (n < N) ? W[(size_t)n*K + kt+cc] : 0.f;
    }
    __syncthreads();
    #pragma unroll
    for (int kk=0;kk<16;kk++){
      float4 a4 = *(const float4*)&As[kk][ty<<2];
      float4 w4 = *(const float4*)&Ws[kk][tx<<2];
      float av[4] = {a4.x,a4.y,a4.z,a4.w};
      float wv[4] = {w4.x,w4.y,w4.z,w4.w};
      #pragma unroll
      for (int a=0;a<4;a++)
        #pragma unroll
        for (int bb=0;bb<4;bb++) acc[a][bb] = fmaf(av[a], wv[bb], acc[a][bb]);
    }
    __syncthreads();
  }
  #pragma unroll
  for (int a=0;a<4;a++){
    int m = m0 + (ty<<2) + a;
    #pragma unroll
    for (int bb=0;bb<4;bb++){
      int n = n0 + (tx<<2) + bb;
      if (n >= N) continue;
      float v = acc[a][bb];
      if (bias) v += bias[n];
      if (ACT==1) v = geluf(v);
      C[(size_t)m*ldc + n] = v;
    }
  }
}

// ---------------- causal depthwise conv (k=4) + bias + silu ----------------
__global__ __launch_bounds__(256) void conv_kernel(const float* __restrict__ xraw,
  const float* __restrict__ cw, const float* __restrict__ cb, float* __restrict__ xc)
{
  int gid = blockIdx.x*256 + threadIdx.x;   // MG*288
  int ch = gid % CONVD;
  int m  = gid / CONVD;
  int t  = m & 4095;
  float acc = cb[ch];
  #pragma unroll
  for (int k=0;k<4;k++){
    int tt = t - 3 + k;
    if (tt >= 0) acc = fmaf(cw[ch*4+k], xraw[(size_t)(m-3+k)*CONVD + ch], acc);
  }
  xc[gid] = acc / (1.0f + expf(-acc));
}

// ---------------- SSD chunk-local: A-cumsum, Y_diag, chunk states ----------------
__global__ __launch_bounds__(256) void ssd_local_kernel(
  const float* __restrict__ xconv, const float* __restrict__ dtsp,
  const float* __restrict__ Alog,
  float* __restrict__ ydiag, float* __restrict__ states_g,
  float* __restrict__ acs_g, float* __restrict__ atot_g)
{
  __shared__ float Bs[64][17], Cs[64][17];
  __shared__ float X[64][64];
  __shared__ float S[64][64];
  __shared__ float acs_s[64], wdec[64], dts[64];
  const int bx = blockIdx.x;                 // bl*256 + c*4 + h
  const int h = bx & 3, c = (bx>>2)&63, bl = bx>>8;
  const int tid = threadIdx.x;
  const int tokbase = (bl<<12) + (c<<6);

  if (tid < 64) {
    float dt = dtsp[(size_t)(tokbase+tid)*NHEADS + h];
    dts[tid] = dt;
    float xsc = -expf(Alog[h]) * dt;
    #pragma unroll
    for (int off=1; off<64; off<<=1){ float v = __shfl_up(xsc, off); if (tid >= off) xsc += v; }
    acs_s[tid] = xsc;
  }
  __syncthreads();
  const float atotv = acs_s[63];
  if (tid < 64) {
    wdec[tid] = expf(atotv - acs_s[tid]);
    acs_g[(size_t)bx*64 + tid] = acs_s[tid];
    if (tid==0) atot_g[bx] = atotv;
  }
  #pragma unroll
  for (int i=0;i<16;i++){ int e = tid + (i<<8); int l = e>>6, p = e&63;
    X[l][p] = xconv[(size_t)(tokbase+l)*CONVD + h*HD + p] * dts[l];
  }
  #pragma unroll
  for (int i=0;i<4;i++){ int e = tid + (i<<8); int l = e>>4, n = e&15;
    const float* row = &xconv[(size_t)(tokbase+l)*CONVD + DIN];
    Bs[l][n] = row[n];
    Cs[l][n] = row[DSTATE + n];
  }
  __syncthreads();
  {
    int s = tid & 63, lr = tid >> 6;
    #pragma unroll
    for (int i=0;i<16;i++){
      int l = lr + (i<<2);
      float v = 0.0f;
      if (s <= l) {
        float dot = 0.f;
        #pragma unroll
        for (int n=0;n<16;n++) dot = fmaf(Cs[l][n], Bs[s][n], dot);
        v = expf(acs_s[l]-acs_s[s]) * dot;
      }
      S[l][s] = v;
    }
  }
  __syncthreads();
  {
    int p = tid & 63, lr = tid >> 6;
    #pragma unroll
    for (int i=0;i<16;i++){
      int l = lr + (i<<2);
      float acc = 0.f;
      for (int s=0;s<=l;s++) acc = fmaf(S[l][s], X[s][p], acc);
      ydiag[(size_t)(tokbase+l)*DIN + h*HD + p] = acc;
    }
  }
  {
    int n = tid & 15, pg = tid >> 4;
    #pragma unroll
    for (int i=0;i<4;i++){
      int p = pg + (i<<4);
      float acc = 0.f;
      #pragma unroll
      for (int l=0;l<64;l++) acc = fmaf(Bs[l][n]*wdec[l], X[l][p], acc);
      states_g[((size_t)bx<<10) + p*16 + n] = acc;
    }
  }
}

// ---------------- inter-chunk state scan (IN-PLACE: states -> prior-state) ----------------
__global__ __launch_bounds__(256) void scan_kernel(float* __restrict__ states,
  const float* __restrict__ atot)
{
  int gid = blockIdx.x*256 + threadIdx.x;   // BG*4096 = bl*4096 + h*1024 + inner
  int inner = gid & 1023;
  int h = (gid>>10)&3;
  int bl = gid>>12;
  float S = 0.0f;
  for (int c=0;c<NCH;c++){
    int bx = ((bl*NCH + c)<<2) + h;
    size_t idx = ((size_t)bx<<10) + inner;
    float tmp = states[idx];
    states[idx] = S;
    S = expf(atot[bx])*S + tmp;
  }
}

// ---------------- Y_off + D residual ----------------
__global__ __launch_bounds__(256) void yoff_kernel(
  const float* __restrict__ xconv, const float* __restrict__ sscan,
  const float* __restrict__ acs_g, const float* __restrict__ Dp,
  float* __restrict__ y)
{
  __shared__ float Cs[64][17];
  __shared__ float St[64][17];
  __shared__ float acs_s[64];
  const int bx = blockIdx.x;
  const int h = bx&3, c = (bx>>2)&63, bl = bx>>8;
  const int tid = threadIdx.x;
  const int tokbase = (bl<<12)+(c<<6);
  #pragma unroll
  for (int i=0;i<4;i++){
    int e = tid + (i<<8);
    int l = e>>4, n = e&15;
    Cs[l][n] = xconv[(size_t)(tokbase+l)*CONVD + DIN + DSTATE + n];
    St[l][n] = sscan[((size_t)bx<<10) + e];    // e = p*16+n, l plays role of p
  }
  if (tid<64) acs_s[tid] = acs_g[(size_t)bx*64+tid];
  __syncthreads();
  const float Dh = Dp[h];
  int p = tid&63, lr = tid>>6;
  #pragma unroll
  for (int i=0;i<16;i++){
    int l = lr + (i<<2);
    float dot = 0.f;
    #pragma unroll
    for (int n=0;n<16;n++) dot = fmaf(Cs[l][n], St[p][n], dot);
    size_t idx = (size_t)(tokbase+l)*DIN + h*HD + p;
    float xo = xconv[(size_t)(tokbase+l)*CONVD + h*HD + p];
    y[idx] = y[idx] + expf(acs_s[l])*dot + Dh*xo;
  }
}

// ---------------- gated RMSNorm (y, z -> z holds normalized output) ----------------
__global__ __launch_bounds__(256) void norm_kernel(const float* __restrict__ y,
  float* __restrict__ z, const float* __restrict__ nw)
{
  int m = blockIdx.x, t = threadIdx.x;
  size_t idx = (size_t)m*DIN + t;
  float yv = y[idx], zv = z[idx];
  float yf = yv * (zv / (1.0f + expf(-zv)));
  float ss = yf*yf;
  #pragma unroll
  for (int off=32; off; off>>=1) ss += __shfl_xor(ss, off);
  __shared__ float red[4];
  if ((t&63)==0) red[t>>6] = ss;
  __syncthreads();
  float tot = red[0]+red[1]+red[2]+red[3];
  float sc = 1.0f / sqrtf(tot*(1.0f/DIN) + 1e-5f);
  z[idx] = yf*sc*nw[t];
}

// ---------------- concat fwd + reversed bwd (group-local) ----------------
__global__ __launch_bounds__(256) void concat_kernel(const float* __restrict__ fa,
  const float* __restrict__ fb, float* __restrict__ cat)
{
  int gid = blockIdx.x*256 + threadIdx.x;   // MG*256
  int m = gid >> 8, k = gid & 255;
  int bl = m >> 12, t = m & 4095;
  cat[gid] = (k < 128) ? fa[((size_t)m<<7) + k]
                       : fb[((size_t)(((bl<<12) | (4095-t)))<<7) + (k-128)];
}

// ---------------- sample = lm + noise*exp(0.5*lv) ----------------
__global__ __launch_bounds__(256) void sample_kernel(const float* __restrict__ lm,
  const float* __restrict__ lv, const float* __restrict__ nz, float* __restrict__ sp)
{
  int gid = blockIdx.x*256 + threadIdx.x;
  sp[gid] = fmaf(nz[gid], expf(0.5f*lv[gid]), lm[gid]);
}

// ---------------- gate + pred ----------------
__global__ __launch_bounds__(256) void gatepred_kernel(
  const float* __restrict__ fused, const float* __restrict__ sample,
  const float* __restrict__ gw, const float* __restrict__ gb,
  const float* __restrict__ ow, const float* __restrict__ ob,
  const float* __restrict__ rg, float* __restrict__ pred)
{
  __shared__ float gws[128][65];
  __shared__ float gbs[128], ows[128];
  const int tid = threadIdx.x;
  #pragma unroll
  for (int i=0;i<32;i++){ int e = tid + (i<<8); gws[e>>6][e&63] = gw[e]; }
  if (tid < 128){ gbs[tid] = gb[tid]; ows[tid] = ow[tid]; }
  __syncthreads();
  const int wave = tid>>6, lane = tid&63;
  const float ob0 = ob[0];
  for (int it=0; it<16; it++){
    int m = blockIdx.x*64 + wave*16 + it;   // local token
    float sv = sample[(size_t)m*LAT + lane];
    float acc0 = gbs[lane], acc1 = gbs[lane+64];
    #pragma unroll
    for (int k=0;k<64;k++){
      float sk = __shfl(sv, k);
      acc0 = fmaf(sk, gws[lane][k], acc0);
      acc1 = fmaf(sk, gws[lane+64][k], acc1);
    }
    float f0 = fused[(size_t)m*128 + lane], f1 = fused[(size_t)m*128 + 64 + lane];
    float cval = f0*sigm(acc0)*ows[lane] + f1*sigm(acc1)*ows[lane+64];
    #pragma unroll
    for (int off=32; off; off>>=1) cval += __shfl_xor(cval, off);
    if (lane==0) pred[m] = (cval + ob0) * sigm(rg[m & 4095]);
  }
}

extern "C" void kernel_launch(void* const* d_in, const int* in_sizes, int n_in,
                              void* d_out, int out_size, void* d_ws, size_t ws_size,
                              hipStream_t stream)
{
  const float* expr      = (const float*)d_in[0];
  const float* noise     = (const float*)d_in[1];
  const float* expr_w    = (const float*)d_in[2];
  const float* expr_b    = (const float*)d_in[3];
  const float* in_proj_w = (const float*)d_in[4];
  const float* conv_w    = (const float*)d_in[5];
  const float* conv_b    = (const float*)d_in[6];
  const float* dt_bias   = (const float*)d_in[7];
  const float* A_log     = (const float*)d_in[8];
  const float* D_par     = (const float*)d_in[9];
  const float* norm_w    = (const float*)d_in[10];
  const float* out_proj_w= (const float*)d_in[11];
  const float* fusion_w  = (const float*)d_in[12];
  const float* fusion_b  = (const float*)d_in[13];
  const float* lm_w      = (const float*)d_in[14];
  const float* lm_b      = (const float*)d_in[15];
  const float* lv_w      = (const float*)d_in[16];
  const float* lv_b      = (const float*)d_in[17];
  const float* gate_w    = (const float*)d_in[18];
  const float* gate_b    = (const float*)d_in[19];
  const float* outp_w    = (const float*)d_in[20];
  const float* outp_b    = (const float*)d_in[21];
  const float* reg_gate  = (const float*)d_in[22];

  // ---- pick largest batch-group that fits the workspace ----
  int BG = 0;
  const int cands[5] = {16, 8, 4, 2, 1};
  for (int ci = 0; ci < 5; ci++) {
    int c = cands[ci];
    size_t MG = (size_t)c * LSEQ;
    size_t need = (MG*(128+128+256+288+288+4+4+64) + (size_t)c*256) * sizeof(float);
    if (need <= ws_size) { BG = c; break; }
  }
  if (!BG) return;
  const size_t MG = (size_t)BG * LSEQ;

  float* ws = (float*)d_ws;
  float* actA  = ws;                               // MG*128
  float* actB  = actA  + MG*128;                   // MG*128
  float* zbuf  = actB  + MG*128;                   // MG*256  (z; later concat buffer)
  float* xraw  = zbuf  + MG*256;                   // MG*288  (pre-conv xBC; later ydiag; later fused)
  float* xconv = xraw  + MG*288;                   // MG*288
  float* dtsp  = xconv + MG*288;                   // MG*4
  float* acs   = dtsp  + MG*4;                     // MG*4
  float* atot  = acs   + MG*4;                     // BG*256
  float* states= atot  + (size_t)BG*256;           // MG*64 (in-place scan)
  float* ydiag = xraw;                             // alias: xraw dead after conv
  float* fusedb= xraw;                             // alias: ydiag dead after layer loop

  float* out_pred_g = (float*)d_out;
  float* out_lm_g   = out_pred_g + (size_t)16*LSEQ;
  float* out_lv_g   = out_lm_g   + (size_t)16*LSEQ*LAT;
  float* out_samp_g = out_lv_g   + (size_t)16*LSEQ*LAT;

  for (int b0 = 0; b0 < 16; b0 += BG) {
    float* out_pred = out_pred_g + (size_t)b0*LSEQ;
    float* out_lm   = out_lm_g   + (size_t)b0*LSEQ*LAT;
    float* out_lv   = out_lv_g   + (size_t)b0*LSEQ*LAT;
    float* out_samp = out_samp_g + (size_t)b0*LSEQ*LAT;
    const float* nz = noise     + (size_t)b0*LSEQ*LAT;

    embed_kernel<<<(MG*128)/256, 256, 0, stream>>>(expr + (size_t)b0*LSEQ, expr_w, expr_b, actA, actB);

    for (int li = 0; li < 4; li++) {
      float* u = (li < 2) ? actA : actB;
      const float* Wi  = in_proj_w + (size_t)li*DPROJ*HMOD;
      const float* cw  = conv_w + (size_t)li*CONVD*4;
      const float* cb  = conv_b + (size_t)li*CONVD;
      const float* dtb = dt_bias + (size_t)li*NHEADS;
      const float* Al  = A_log + (size_t)li*NHEADS;
      const float* Dl  = D_par + (size_t)li*NHEADS;
      const float* nw  = norm_w + (size_t)li*DIN;
      const float* Wo  = out_proj_w + (size_t)li*HMOD*DIN;

      gemm_in_kernel<<<dim3(MG/64, 9), 256, 0, stream>>>(u, Wi, dtb, zbuf, xraw, dtsp);
      conv_kernel<<<(MG*CONVD)/256, 256, 0, stream>>>(xraw, cw, cb, xconv);
      ssd_local_kernel<<<BG*NCH*NHEADS, 256, 0, stream>>>(xconv, dtsp, Al, ydiag, states, acs, atot);
      scan_kernel<<<(BG*LSEQ)/256, 256, 0, stream>>>(states, atot);
      yoff_kernel<<<BG*NCH*NHEADS, 256, 0, stream>>>(xconv, states, acs, Dl, ydiag);
      norm_kernel<<<MG, 256, 0, stream>>>(ydiag, zbuf, nw);
      gemm_plain<0><<<dim3(MG/64, 2), 256, 0, stream>>>(zbuf, DIN, Wo, nullptr, u, HMOD, HMOD, DIN);
    }

    concat_kernel<<<(MG*256)/256, 256, 0, stream>>>(actA, actB, zbuf);
    gemm_plain<1><<<dim3(MG/64, 2), 256, 0, stream>>>(zbuf, DIN, fusion_w, fusion_b, fusedb, HMOD, HMOD, DIN);
    gemm_plain<0><<<dim3(MG/64, 1), 256, 0, stream>>>(fusedb, HMOD, lm_w, lm_b, out_lm, LAT, LAT, HMOD);
    gemm_plain<0><<<dim3(MG/64, 1), 256, 0, stream>>>(fusedb, HMOD, lv_w, lv_b, out_lv, LAT, LAT, HMOD);
    sample_kernel<<<(MG*LAT)/256, 256, 0, stream>>>(out_lm, out_lv, nz, out_samp);
    gatepred_kernel<<<MG/64, 256, 0, stream>>>(fusedb, out_samp, gate_w, gate_b, outp_w, outp_b, reg_gate, out_pred);
  }
}

// Round 3
// 1604.347 us; speedup vs baseline: 2.1746x; 2.1746x over previous
//
#include <hip/hip_runtime.h>
#include <math.h>

#define HMOD 128
#define DIN 256
#define NHEADS 4
#define HD 64
#define DSTATE 16
#define NCH 64
#define CONVD 288
#define DPROJ 548
#define LAT 64
#define LSEQ 4096

typedef __attribute__((ext_vector_type(8))) short bf16x8;
typedef __attribute__((ext_vector_type(4))) float f32x4;

__device__ __forceinline__ float sigm(float x){ return 1.0f/(1.0f+expf(-x)); }
__device__ __forceinline__ float softplusf(float x){ return (x>20.0f)? x : log1pf(expf(x)); }
__device__ __forceinline__ float geluf(float x){ return 0.5f*x*(1.0f+erff(x*0.70710678118654752440f)); }
__device__ __forceinline__ unsigned short f2bf(float x){
  unsigned int u = __float_as_uint(x);
  return (unsigned short)((u + 0x7FFFu + ((u>>16)&1u)) >> 16);
}
__device__ __forceinline__ float bf2f(unsigned short h){
  return __uint_as_float(((unsigned int)h)<<16);
}

// ---------------- fp32 -> bf16 weight conversion ----------------
__global__ __launch_bounds__(256) void cvt_kernel(const float* __restrict__ in,
  unsigned short* __restrict__ out, int n)
{
  int i = blockIdx.x*256 + threadIdx.x;
  if (i < n) out[i] = f2bf(in[i]);
}

// ---------------- embedding (bf16 fwd + reversed bwd) ----------------
__global__ __launch_bounds__(256) void embed_kernel(const float* __restrict__ expr,
    const float* __restrict__ ew, const float* __restrict__ eb,
    unsigned short* __restrict__ actA, unsigned short* __restrict__ actB)
{
  int gid = blockIdx.x*256 + threadIdx.x;    // MG*128
  int m = gid >> 7, hh = gid & 127;
  int bl = m >> 12, g = m & 4095;
  unsigned short v = f2bf(expr[m]*ew[hh] + eb[hh]);
  actA[gid] = v;
  actB[(size_t)(((bl<<12) | (4095-g))<<7) + hh] = v;
}

// ---------------- MFMA GEMM: C[M,N] = A[M,K] @ W[N,K]^T ----------------
// EPI 0: bf16 out.  1: in_proj routing (z fp32, xBC fp32, dt softplus).
// EPI 2: bias+gelu -> bf16.  3: bias -> fp32 out.
template<int KDIM, int EPI>
__global__ __launch_bounds__(256) void gemm_mfma(
    const unsigned short* __restrict__ A,
    const unsigned short* __restrict__ Wb,
    const float* __restrict__ bias,
    float* __restrict__ out_f, float* __restrict__ out_f2, float* __restrict__ out_f3,
    unsigned short* __restrict__ out_b,
    int N, int ldc)
{
  __shared__ unsigned short Ws[64*(KDIM+8)];
  const int tid = threadIdx.x;
  const int n0 = blockIdx.x<<6;
  const int m0 = blockIdx.y<<7;
  const int CH = 64*KDIM/8;
  for (int c = tid; c < CH; c += 256){
    int row = c/(KDIM/8), kc = (c%(KDIM/8))*8;
    int n = n0 + row;
    bf16x8 v = {0,0,0,0,0,0,0,0};
    if (n < N) v = *(const bf16x8*)&Wb[(size_t)n*KDIM + kc];
    *(bf16x8*)&Ws[row*(KDIM+8) + kc] = v;
  }
  __syncthreads();
  const int wid = tid>>6, lane = tid&63;
  const int la = lane&15, kq = lane>>4;
  const int mw = m0 + wid*32;
  f32x4 acc[2][4] = {};
  #pragma unroll
  for (int k0 = 0; k0 < KDIM; k0 += 32){
    bf16x8 af[2];
    #pragma unroll
    for (int mf=0; mf<2; mf++)
      af[mf] = *(const bf16x8*)&A[(size_t)(mw + mf*16 + la)*KDIM + k0 + kq*8];
    #pragma unroll
    for (int nf=0; nf<4; nf++){
      bf16x8 bfr = *(const bf16x8*)&Ws[(nf*16 + la)*(KDIM+8) + k0 + kq*8];
      #pragma unroll
      for (int mf=0; mf<2; mf++)
        acc[mf][nf] = __builtin_amdgcn_mfma_f32_16x16x32_bf16(af[mf], bfr, acc[mf][nf], 0,0,0);
    }
  }
  #pragma unroll
  for (int mf=0; mf<2; mf++){
    #pragma unroll
    for (int nf=0; nf<4; nf++){
      #pragma unroll
      for (int r=0; r<4; r++){
        int m = mw + mf*16 + kq*4 + r;
        int n = n0 + nf*16 + la;
        float v = acc[mf][nf][r];
        if (EPI==1){
          if (n < DIN)             out_f [(size_t)m*DIN   + n]        = v;
          else if (n < DIN+CONVD)  out_f2[(size_t)m*CONVD + (n-DIN)]  = v;
          else if (n < DPROJ)      out_f3[(size_t)m*NHEADS + (n-DIN-CONVD)] = softplusf(v + bias[n-DIN-CONVD]);
        } else if (EPI==0){
          out_b[(size_t)m*ldc + n] = f2bf(v);
        } else if (EPI==2){
          out_b[(size_t)m*ldc + n] = f2bf(geluf(v + bias[n]));
        } else {
          out_f[(size_t)m*ldc + n] = v + bias[n];
        }
      }
    }
  }
}

// ---------------- causal depthwise conv (k=4) + bias + silu ----------------
__global__ __launch_bounds__(256) void conv_kernel(const float* __restrict__ xraw,
  const float* __restrict__ cw, const float* __restrict__ cb, float* __restrict__ xc)
{
  int gid = blockIdx.x*256 + threadIdx.x;   // MG*288
  int ch = gid % CONVD;
  int m  = gid / CONVD;
  int t  = m & 4095;
  float acc = cb[ch];
  #pragma unroll
  for (int k=0;k<4;k++){
    int tt = t - 3 + k;
    if (tt >= 0) acc = fmaf(cw[ch*4+k], xraw[(size_t)(m-3+k)*CONVD + ch], acc);
  }
  xc[gid] = acc / (1.0f + expf(-acc));
}

// ---------------- SSD chunk-local ----------------
__global__ __launch_bounds__(256) void ssd_local_kernel(
  const float* __restrict__ xconv, const float* __restrict__ dtsp,
  const float* __restrict__ Alog,
  float* __restrict__ ydiag, float* __restrict__ states_g,
  float* __restrict__ acs_g, float* __restrict__ atot_g)
{
  __shared__ float Bs[64][17], Cs[64][17];
  __shared__ float X[64][68];
  __shared__ float S[64][65];
  __shared__ float acs_s[64], wdec[64], dts[64];
  const int bx = blockIdx.x;                 // bl*256 + c*4 + h
  const int h = bx & 3, c = (bx>>2)&63, bl = bx>>8;
  const int tid = threadIdx.x;
  const int tokbase = (bl<<12) + (c<<6);

  if (tid < 64) {
    float dt = dtsp[(size_t)(tokbase+tid)*NHEADS + h];
    dts[tid] = dt;
    float xsc = -__expf(Alog[h]) * dt;
    #pragma unroll
    for (int off=1; off<64; off<<=1){ float v = __shfl_up(xsc, off); if (tid >= off) xsc += v; }
    acs_s[tid] = xsc;
  }
  __syncthreads();
  const float atotv = acs_s[63];
  if (tid < 64) {
    wdec[tid] = __expf(atotv - acs_s[tid]);
    acs_g[(size_t)bx*64 + tid] = acs_s[tid];
    if (tid==0) atot_g[bx] = atotv;
  }
  #pragma unroll
  for (int i=0;i<16;i++){ int e = tid + (i<<8); int l = e>>6, p = e&63;
    X[l][p] = xconv[(size_t)(tokbase+l)*CONVD + h*HD + p] * dts[l];
  }
  #pragma unroll
  for (int i=0;i<4;i++){ int e = tid + (i<<8); int l = e>>4, n = e&15;
    const float* row = &xconv[(size_t)(tokbase+l)*CONVD + DIN];
    Bs[l][n] = row[n];
    Cs[l][n] = row[DSTATE + n];
  }
  __syncthreads();
  // S[l][s] = exp(acs[l]-acs[s]) * (C[l]·B[s]) for s<=l else 0
  {
    int s = tid & 63, lr = tid >> 6;
    float bsv[16];
    #pragma unroll
    for (int n=0;n<16;n++) bsv[n] = Bs[s][n];
    const float as = acs_s[s];
    #pragma unroll
    for (int i=0;i<16;i++){
      int l = lr + (i<<2);
      float v = 0.0f;
      if (s <= l) {
        float dot = 0.f;
        #pragma unroll
        for (int n=0;n<16;n++) dot = fmaf(Cs[l][n], bsv[n], dot);
        v = __expf(acs_s[l]-as) * dot;
      }
      S[l][s] = v;
    }
  }
  __syncthreads();
  // Y_diag = S · X  (4x4 register tile per thread)
  {
    const int pt = tid & 15, lt = tid >> 4;
    const int p0 = pt<<2, l0 = lt<<2;
    float acc[4][4] = {};
    for (int s=0;s<64;s++){
      float4 x4 = *(const float4*)&X[s][p0];
      float sv[4];
      #pragma unroll
      for (int i=0;i<4;i++) sv[i] = S[l0+i][s];
      #pragma unroll
      for (int i=0;i<4;i++){
        acc[i][0] = fmaf(sv[i], x4.x, acc[i][0]);
        acc[i][1] = fmaf(sv[i], x4.y, acc[i][1]);
        acc[i][2] = fmaf(sv[i], x4.z, acc[i][2]);
        acc[i][3] = fmaf(sv[i], x4.w, acc[i][3]);
      }
    }
    #pragma unroll
    for (int i=0;i<4;i++){
      float4 o; o.x=acc[i][0]; o.y=acc[i][1]; o.z=acc[i][2]; o.w=acc[i][3];
      *(float4*)&ydiag[(size_t)(tokbase+l0+i)*DIN + h*HD + p0] = o;
    }
  }
  // states[p][n] = sum_l B[l][n]*wdec[l]*X[l][p]
  {
    const int n = tid & 15, pg = tid >> 4;
    const int p0 = pg<<2;
    float a0=0.f,a1=0.f,a2=0.f,a3=0.f;
    for (int l=0;l<64;l++){
      float bw = Bs[l][n]*wdec[l];
      float4 x4 = *(const float4*)&X[l][p0];
      a0 = fmaf(bw, x4.x, a0); a1 = fmaf(bw, x4.y, a1);
      a2 = fmaf(bw, x4.z, a2); a3 = fmaf(bw, x4.w, a3);
    }
    size_t base = ((size_t)bx<<10);
    states_g[base + (size_t)(p0+0)*16 + n] = a0;
    states_g[base + (size_t)(p0+1)*16 + n] = a1;
    states_g[base + (size_t)(p0+2)*16 + n] = a2;
    states_g[base + (size_t)(p0+3)*16 + n] = a3;
  }
}

// ---------------- inter-chunk state scan (in place) ----------------
__global__ __launch_bounds__(256) void scan_kernel(float* __restrict__ states,
  const float* __restrict__ atot)
{
  int gid = blockIdx.x*256 + threadIdx.x;   // BG*4096
  int inner = gid & 1023;
  int h = (gid>>10)&3;
  int bl = gid>>12;
  float S = 0.0f;
  for (int c=0;c<NCH;c++){
    int bx = ((bl*NCH + c)<<2) + h;
    size_t idx = ((size_t)bx<<10) + inner;
    float tmp = states[idx];
    states[idx] = S;
    S = __expf(atot[bx])*S + tmp;
  }
}

// ---------------- Y_off + D residual ----------------
__global__ __launch_bounds__(256) void yoff_kernel(
  const float* __restrict__ xconv, const float* __restrict__ sscan,
  const float* __restrict__ acs_g, const float* __restrict__ Dp,
  float* __restrict__ y)
{
  __shared__ float Cst[16][68];   // [n][l]
  __shared__ float Stt[16][68];   // [n][p]
  __shared__ float acs_s[64];
  const int bx = blockIdx.x;
  const int h = bx&3, c = (bx>>2)&63, bl = bx>>8;
  const int tid = threadIdx.x;
  const int tokbase = (bl<<12)+(c<<6);
  #pragma unroll
  for (int i=0;i<4;i++){
    int e = tid + (i<<8);
    int l = e>>4, n = e&15;
    Cst[n][l] = xconv[(size_t)(tokbase+l)*CONVD + DIN + DSTATE + n];
    Stt[n][l] = sscan[((size_t)bx<<10) + e];   // e = p*16+n, l plays role of p
  }
  if (tid<64) acs_s[tid] = acs_g[(size_t)bx*64+tid];
  __syncthreads();
  const float Dh = Dp[h];
  const int pt = tid&15, lt = tid>>4;
  const int p0 = pt<<2, l0 = lt<<2;
  float acc[4][4] = {};
  #pragma unroll
  for (int n=0;n<16;n++){
    float4 st4 = *(const float4*)&Stt[n][p0];
    float cv[4];
    #pragma unroll
    for (int i=0;i<4;i++) cv[i] = Cst[n][l0+i];
    #pragma unroll
    for (int i=0;i<4;i++){
      acc[i][0] = fmaf(cv[i], st4.x, acc[i][0]);
      acc[i][1] = fmaf(cv[i], st4.y, acc[i][1]);
      acc[i][2] = fmaf(cv[i], st4.z, acc[i][2]);
      acc[i][3] = fmaf(cv[i], st4.w, acc[i][3]);
    }
  }
  #pragma unroll
  for (int i=0;i<4;i++){
    int l = l0+i;
    float ea = __expf(acs_s[l]);
    size_t rowx = (size_t)(tokbase+l)*CONVD + h*HD + p0;
    size_t rowy = (size_t)(tokbase+l)*DIN  + h*HD + p0;
    float4 x4 = *(const float4*)&xconv[rowx];
    float4 y4 = *(const float4*)&y[rowy];
    y4.x += ea*acc[i][0] + Dh*x4.x;
    y4.y += ea*acc[i][1] + Dh*x4.y;
    y4.z += ea*acc[i][2] + Dh*x4.z;
    y4.w += ea*acc[i][3] + Dh*x4.w;
    *(float4*)&y[rowy] = y4;
  }
}

// ---------------- gated RMSNorm -> bf16 ----------------
__global__ __launch_bounds__(256) void norm_kernel(const float* __restrict__ y,
  const float* __restrict__ z, const float* __restrict__ nw,
  unsigned short* __restrict__ outb)
{
  int m = blockIdx.x, t = threadIdx.x;
  size_t idx = (size_t)m*DIN + t;
  float yv = y[idx], zv = z[idx];
  float yf = yv * (zv / (1.0f + expf(-zv)));
  float ss = yf*yf;
  #pragma unroll
  for (int off=32; off; off>>=1) ss += __shfl_xor(ss, off);
  __shared__ float red[4];
  if ((t&63)==0) red[t>>6] = ss;
  __syncthreads();
  float tot = red[0]+red[1]+red[2]+red[3];
  float sc = 1.0f / sqrtf(tot*(1.0f/DIN) + 1e-5f);
  outb[idx] = f2bf(yf*sc*nw[t]);
}

// ---------------- concat fwd + reversed bwd (bf16) ----------------
__global__ __launch_bounds__(256) void concat_kernel(const unsigned short* __restrict__ fa,
  const unsigned short* __restrict__ fb, unsigned short* __restrict__ cat)
{
  int gid = blockIdx.x*256 + threadIdx.x;   // MG*256
  int m = gid >> 8, k = gid & 255;
  int bl = m >> 12, t = m & 4095;
  cat[gid] = (k < 128) ? fa[((size_t)m<<7) + k]
                       : fb[((size_t)(((bl<<12) | (4095-t)))<<7) + (k-128)];
}

// ---------------- sample = lm + noise*exp(0.5*lv) ----------------
__global__ __launch_bounds__(256) void sample_kernel(const float* __restrict__ lm,
  const float* __restrict__ lv, const float* __restrict__ nz, float* __restrict__ sp)
{
  int gid = blockIdx.x*256 + threadIdx.x;
  sp[gid] = fmaf(nz[gid], expf(0.5f*lv[gid]), lm[gid]);
}

// ---------------- gate + pred (fused is bf16) ----------------
__global__ __launch_bounds__(256) void gatepred_kernel(
  const unsigned short* __restrict__ fused, const float* __restrict__ sample,
  const float* __restrict__ gw, const float* __restrict__ gb,
  const float* __restrict__ ow, const float* __restrict__ ob,
  const float* __restrict__ rg, float* __restrict__ pred)
{
  __shared__ float gws[128][65];
  __shared__ float gbs[128], ows[128];
  const int tid = threadIdx.x;
  #pragma unroll
  for (int i=0;i<32;i++){ int e = tid + (i<<8); gws[e>>6][e&63] = gw[e]; }
  if (tid < 128){ gbs[tid] = gb[tid]; ows[tid] = ow[tid]; }
  __syncthreads();
  const int wave = tid>>6, lane = tid&63;
  const float ob0 = ob[0];
  for (int it=0; it<16; it++){
    int m = blockIdx.x*64 + wave*16 + it;
    float sv = sample[(size_t)m*LAT + lane];
    float acc0 = gbs[lane], acc1 = gbs[lane+64];
    #pragma unroll
    for (int k=0;k<64;k++){
      float sk = __shfl(sv, k);
      acc0 = fmaf(sk, gws[lane][k], acc0);
      acc1 = fmaf(sk, gws[lane+64][k], acc1);
    }
    float f0 = bf2f(fused[(size_t)m*128 + lane]);
    float f1 = bf2f(fused[(size_t)m*128 + 64 + lane]);
    float cval = f0*sigm(acc0)*ows[lane] + f1*sigm(acc1)*ows[lane+64];
    #pragma unroll
    for (int off=32; off; off>>=1) cval += __shfl_xor(cval, off);
    if (lane==0) pred[m] = (cval + ob0) * sigm(rg[m & 4095]);
  }
}

extern "C" void kernel_launch(void* const* d_in, const int* in_sizes, int n_in,
                              void* d_out, int out_size, void* d_ws, size_t ws_size,
                              hipStream_t stream)
{
  const float* expr      = (const float*)d_in[0];
  const float* noise     = (const float*)d_in[1];
  const float* expr_w    = (const float*)d_in[2];
  const float* expr_b    = (const float*)d_in[3];
  const float* in_proj_w = (const float*)d_in[4];
  const float* conv_w    = (const float*)d_in[5];
  const float* conv_b    = (const float*)d_in[6];
  const float* dt_bias   = (const float*)d_in[7];
  const float* A_log     = (const float*)d_in[8];
  const float* D_par     = (const float*)d_in[9];
  const float* norm_w    = (const float*)d_in[10];
  const float* out_proj_w= (const float*)d_in[11];
  const float* fusion_w  = (const float*)d_in[12];
  const float* fusion_b  = (const float*)d_in[13];
  const float* lm_w      = (const float*)d_in[14];
  const float* lm_b      = (const float*)d_in[15];
  const float* lv_w      = (const float*)d_in[16];
  const float* lv_b      = (const float*)d_in[17];
  const float* gate_w    = (const float*)d_in[18];
  const float* gate_b    = (const float*)d_in[19];
  const float* outp_w    = (const float*)d_in[20];
  const float* outp_b    = (const float*)d_in[21];
  const float* reg_gate  = (const float*)d_in[22];

  const size_t WBYTES = 921600;  // bf16 weights region
  int BG = 0;
  const int cands[5] = {16, 8, 4, 2, 1};
  for (int ci = 0; ci < 5; ci++) {
    int c2 = cands[ci];
    size_t MGc = (size_t)c2 * LSEQ;
    size_t need = WBYTES + MGc*4640 + (size_t)c2*1024;
    if (need <= ws_size) { BG = c2; break; }
  }
  if (!BG) return;
  const size_t MG = (size_t)BG * LSEQ;

  unsigned short* wip = (unsigned short*)d_ws;      // 4*548*128 = 280576
  unsigned short* wop = wip + 280576;               // 4*128*256 = 131072
  unsigned short* wfu = wop + 131072;               // 128*256   = 32768
  unsigned short* wlm = wfu + 32768;                // 64*128    = 8192
  unsigned short* wlv = wlm + 8192;                 // 64*128    = 8192
  float* zbuf  = (float*)((char*)d_ws + WBYTES);    // MG*256
  float* xraw  = zbuf  + MG*256;                    // MG*288 (later ydiag)
  float* xconv = xraw  + MG*288;                    // MG*288
  float* dtsp  = xconv + MG*288;                    // MG*4
  float* acs   = dtsp  + MG*4;                      // MG*4
  float* atot  = acs   + MG*4;                      // BG*256
  float* states= atot  + (size_t)BG*256;            // MG*64
  unsigned short* actAbf = (unsigned short*)(states + MG*64);  // MG*128
  unsigned short* actBbf = actAbf + MG*128;                    // MG*128
  unsigned short* znorm  = actBbf + MG*128;                    // MG*256
  unsigned short* catbf  = znorm;    // alias (znorm dead after layer loop)
  unsigned short* fusedbf= actAbf;   // alias (actA dead after concat)
  float* ydiag = xraw;

  float* out_pred_g = (float*)d_out;
  float* out_lm_g   = out_pred_g + (size_t)16*LSEQ;
  float* out_lv_g   = out_lm_g   + (size_t)16*LSEQ*LAT;
  float* out_samp_g = out_lv_g   + (size_t)16*LSEQ*LAT;

  // weight conversion (once per launch)
  cvt_kernel<<<(280576+255)/256, 256, 0, stream>>>(in_proj_w,  wip, 280576);
  cvt_kernel<<<131072/256,       256, 0, stream>>>(out_proj_w, wop, 131072);
  cvt_kernel<<<32768/256,        256, 0, stream>>>(fusion_w,   wfu, 32768);
  cvt_kernel<<<8192/256,         256, 0, stream>>>(lm_w,       wlm, 8192);
  cvt_kernel<<<8192/256,         256, 0, stream>>>(lv_w,       wlv, 8192);

  for (int b0 = 0; b0 < 16; b0 += BG) {
    float* out_pred = out_pred_g + (size_t)b0*LSEQ;
    float* out_lm   = out_lm_g   + (size_t)b0*LSEQ*LAT;
    float* out_lv   = out_lv_g   + (size_t)b0*LSEQ*LAT;
    float* out_samp = out_samp_g + (size_t)b0*LSEQ*LAT;
    const float* nz = noise      + (size_t)b0*LSEQ*LAT;

    embed_kernel<<<(MG*128)/256, 256, 0, stream>>>(expr + (size_t)b0*LSEQ, expr_w, expr_b, actAbf, actBbf);

    for (int li = 0; li < 4; li++) {
      unsigned short* u = (li < 2) ? actAbf : actBbf;
      const unsigned short* Wi = wip + (size_t)li*DPROJ*HMOD;
      const unsigned short* Wo = wop + (size_t)li*HMOD*DIN;
      const float* cw  = conv_w + (size_t)li*CONVD*4;
      const float* cb  = conv_b + (size_t)li*CONVD;
      const float* dtb = dt_bias + (size_t)li*NHEADS;
      const float* Al  = A_log + (size_t)li*NHEADS;
      const float* Dl  = D_par + (size_t)li*NHEADS;
      const float* nw  = norm_w + (size_t)li*DIN;

      gemm_mfma<128,1><<<dim3(9, MG/128), 256, 0, stream>>>(u, Wi, dtb, zbuf, xraw, dtsp, nullptr, DPROJ, 0);
      conv_kernel<<<(MG*CONVD)/256, 256, 0, stream>>>(xraw, cw, cb, xconv);
      ssd_local_kernel<<<BG*256, 256, 0, stream>>>(xconv, dtsp, Al, ydiag, states, acs, atot);
      scan_kernel<<<(BG*LSEQ)/256, 256, 0, stream>>>(states, atot);
      yoff_kernel<<<BG*256, 256, 0, stream>>>(xconv, states, acs, Dl, ydiag);
      norm_kernel<<<MG, 256, 0, stream>>>(ydiag, zbuf, nw, znorm);
      gemm_mfma<256,0><<<dim3(2, MG/128), 256, 0, stream>>>(znorm, Wo, nullptr, nullptr, nullptr, nullptr, u, HMOD, HMOD);
    }

    concat_kernel<<<(MG*256)/256, 256, 0, stream>>>(actAbf, actBbf, catbf);
    gemm_mfma<256,2><<<dim3(2, MG/128), 256, 0, stream>>>(catbf, wfu, fusion_b, nullptr, nullptr, nullptr, fusedbf, HMOD, HMOD);
    gemm_mfma<128,3><<<dim3(1, MG/128), 256, 0, stream>>>(fusedbf, wlm, lm_b, out_lm, nullptr, nullptr, nullptr, LAT, LAT);
    gemm_mfma<128,3><<<dim3(1, MG/128), 256, 0, stream>>>(fusedbf, wlv, lv_b, out_lv, nullptr, nullptr, nullptr, LAT, LAT);
    sample_kernel<<<(MG*LAT)/256, 256, 0, stream>>>(out_lm, out_lv, nz, out_samp);
    gatepred_kernel<<<MG/64, 256, 0, stream>>>(fusedbf, out_samp, gate_w, gate_b, outp_w, outp_b, reg_gate, out_pred);
  }
}

// Round 4
// 1177.417 us; speedup vs baseline: 2.9632x; 1.3626x over previous
//
#include <hip/hip_runtime.h>
#include <math.h>

#define HMOD 128
#define DIN 256
#define NHEADS 4
#define HD 64
#define DSTATE 16
#define NCH 64
#define CONVD 288
#define DPROJ 548
#define LAT 64
#define LSEQ 4096

typedef __attribute__((ext_vector_type(8))) short bf16x8;
typedef __attribute__((ext_vector_type(4))) float f32x4;
typedef __attribute__((ext_vector_type(4))) unsigned short u16x4;

__device__ __forceinline__ float sigm(float x){ return 1.0f/(1.0f+__expf(-x)); }
__device__ __forceinline__ float siluf(float x){ return x/(1.0f+__expf(-x)); }
__device__ __forceinline__ float softplusf(float x){ return (x>20.0f)? x : log1pf(expf(x)); }
__device__ __forceinline__ float geluf(float x){ return 0.5f*x*(1.0f+erff(x*0.70710678118654752440f)); }
__device__ __forceinline__ unsigned short f2bf(float x){
  unsigned int u = __float_as_uint(x);
  return (unsigned short)((u + 0x7FFFu + ((u>>16)&1u)) >> 16);
}
__device__ __forceinline__ float bf2f(unsigned short h){
  return __uint_as_float(((unsigned int)h)<<16);
}

// ---------------- weight conversion ----------------
__global__ __launch_bounds__(256) void cvt_kernel(const float* __restrict__ in,
  unsigned short* __restrict__ out, int n)
{
  int i = blockIdx.x*256 + threadIdx.x;
  if (i < n) out[i] = f2bf(in[i]);
}
// out_proj with norm_w folded into K-columns: dst[li][n][k] = W[li][n][k]*nw[li][k]
__global__ __launch_bounds__(256) void cvt_nw_kernel(const float* __restrict__ in,
  const float* __restrict__ nw, unsigned short* __restrict__ out, int n)
{
  int i = blockIdx.x*256 + threadIdx.x;
  if (i < n){
    int k = i & 255;
    int li = i >> 15;           // 128*256 per layer
    out[i] = f2bf(in[i]*nw[li*256 + k]);
  }
}

// ---------------- embedding (bf16 fwd + reversed bwd) ----------------
__global__ __launch_bounds__(256) void embed_kernel(const float* __restrict__ expr,
    const float* __restrict__ ew, const float* __restrict__ eb,
    unsigned short* __restrict__ actA, unsigned short* __restrict__ actB)
{
  int gid = blockIdx.x*256 + threadIdx.x;    // MG*128
  int m = gid >> 7, hh = gid & 127;
  int bl = m >> 12, g = m & 4095;
  unsigned short v = f2bf(expr[m]*ew[hh] + eb[hh]);
  actA[gid] = v;
  actB[(size_t)(((bl<<12) | (4095-g))<<7) + hh] = v;
}

// ---------------- MFMA GEMM: C[M,N] = A[M,K] @ W[N,K]^T ----------------
// A-frags preloaded in registers; loop over N-tiles (W staged in LDS).
// EPI 1: in_proj routing (z bf16, xraw bf16, dt softplus fp32)
// EPI 2: fusion (A2 = reversed second half), bias+gelu -> bf16
// EPI 3: bias -> fp32
// EPI 4: out_proj: row-scale by rsqrt(mean(ssq)+eps) -> bf16
template<int KDIM, int NT, int EPI>
__global__ __launch_bounds__(256) void gemm2(
    const unsigned short* __restrict__ A,
    const unsigned short* __restrict__ A2,
    const unsigned short* __restrict__ Wb,
    const float* __restrict__ bias,
    const float* __restrict__ ssqp,
    unsigned short* __restrict__ ob1,
    unsigned short* __restrict__ ob2,
    float* __restrict__ of1,
    int N, int ldc)
{
  __shared__ unsigned short Ws[64*(KDIM+8)];
  const int tid = threadIdx.x;
  const int m0 = blockIdx.x<<7;
  const int wid = tid>>6, lane = tid&63;
  const int la = lane&15, kq = lane>>4;
  const int mw = m0 + wid*32;

  // preload A fragments
  bf16x8 af[KDIM/32][2];
  #pragma unroll
  for (int ki=0; ki<KDIM/32; ki++){
    int k = ki*32 + kq*8;
    #pragma unroll
    for (int mf=0; mf<2; mf++){
      int row = mw + mf*16 + la;
      const unsigned short* src;
      if (EPI==2){
        if (k < 128) src = A + (size_t)row*128 + k;
        else { int bl2=row>>12, t=row&4095; src = A2 + (size_t)(((bl2<<12)|(4095-t)))*128 + (k-128); }
      } else {
        src = A + (size_t)row*KDIM + k;
      }
      af[ki][mf] = *(const bf16x8*)src;
    }
  }
  float scv[2][4];
  if (EPI==4){
    #pragma unroll
    for (int mf=0; mf<2; mf++)
      #pragma unroll
      for (int r=0; r<4; r++){
        int m = mw + mf*16 + kq*4 + r;
        float s = ssqp[m*4]+ssqp[m*4+1]+ssqp[m*4+2]+ssqp[m*4+3];
        scv[mf][r] = rsqrtf(s*(1.0f/256.0f) + 1e-5f);
      }
  }

  const int KD8 = KDIM/8;
  for (int nt=0; nt<NT; nt++){
    int n0 = (blockIdx.y*NT + nt)<<6;
    if (nt) __syncthreads();
    for (int ci = tid; ci < 64*KD8; ci += 256){
      int row = ci/KD8, kc = (ci - row*KD8)*8;
      int n = n0 + row;
      bf16x8 v = {0,0,0,0,0,0,0,0};
      if (n < N) v = *(const bf16x8*)&Wb[(size_t)n*KDIM + kc];
      *(bf16x8*)&Ws[row*(KDIM+8) + kc] = v;
    }
    __syncthreads();
    f32x4 acc[2][4] = {};
    #pragma unroll
    for (int ki=0; ki<KDIM/32; ki++){
      #pragma unroll
      for (int nf=0; nf<4; nf++){
        bf16x8 bfr = *(const bf16x8*)&Ws[(nf*16 + la)*(KDIM+8) + ki*32 + kq*8];
        #pragma unroll
        for (int mf=0; mf<2; mf++)
          acc[mf][nf] = __builtin_amdgcn_mfma_f32_16x16x32_bf16(af[ki][mf], bfr, acc[mf][nf], 0,0,0);
      }
    }
    #pragma unroll
    for (int mf=0; mf<2; mf++){
      #pragma unroll
      for (int nf=0; nf<4; nf++){
        #pragma unroll
        for (int r=0; r<4; r++){
          int m = mw + mf*16 + kq*4 + r;
          int n = n0 + nf*16 + la;
          float v = acc[mf][nf][r];
          if (EPI==1){
            if (n < DIN)            ob1[(size_t)m*DIN + n] = f2bf(v);
            else if (n < DIN+CONVD) ob2[(size_t)m*CONVD + (n-DIN)] = f2bf(v);
            else if (n < DPROJ)     of1[(size_t)m*NHEADS + (n-DIN-CONVD)] = softplusf(v + bias[n-DIN-CONVD]);
          } else if (EPI==2){
            if (n < N) ob1[(size_t)m*ldc + n] = f2bf(geluf(v + bias[n]));
          } else if (EPI==3){
            if (n < N) of1[(size_t)m*ldc + n] = v + bias[n];
          } else if (EPI==4){
            if (n < N) ob1[(size_t)m*ldc + n] = f2bf(v*scv[mf][r]);
          }
        }
      }
    }
  }
}

// ---------------- SSD front: conv(x,B)+silu, A-cumsum, chunk states ----------------
__global__ __launch_bounds__(256) void ssd_front(
  const unsigned short* __restrict__ xraw, const float* __restrict__ dtsp,
  const float* __restrict__ Alog,
  const float* __restrict__ cw, const float* __restrict__ cb,
  float* __restrict__ states_g, float* __restrict__ acs_g, float* __restrict__ atot_g)
{
  __shared__ float X[64][68], Bs[64][17];
  __shared__ float acs_s[64], dts[64], wdec[64];
  const int bx = blockIdx.x;                 // bl*256 + c*4 + h
  const int h = bx & 3, c = (bx>>2)&63, bl = bx>>8;
  const int tid = threadIdx.x;
  const int tokbase = (bl<<12) + (c<<6);

  if (tid < 64) {
    float dt = dtsp[(size_t)(tokbase+tid)*NHEADS + h];
    dts[tid] = dt;
    float xsc = -__expf(Alog[h]) * dt;
    #pragma unroll
    for (int off=1; off<64; off<<=1){ float v = __shfl_up(xsc, off); if (tid >= off) xsc += v; }
    acs_s[tid] = xsc;
    acs_g[(size_t)bx*64 + tid] = xsc;
  }
  __syncthreads();
  const float atotv = acs_s[63];
  if (tid < 64) {
    wdec[tid] = __expf(atotv - acs_s[tid]);
    if (tid==0) atot_g[bx] = atotv;
  }
  // conv+silu for x-slice (64ch) + B (16ch)
  #pragma unroll
  for (int i=0;i<20;i++){
    int e = tid + (i<<8);
    int l = e/80, ci = e - l*80;
    int ch = (ci<64) ? (h<<6)+ci : 256+(ci-64);
    float acc = cb[ch];
    #pragma unroll
    for (int k=0;k<4;k++){
      int t = (c<<6)+l-3+k;
      if (t >= 0) acc = fmaf(cw[ch*4+k], bf2f(xraw[(size_t)((bl<<12)+t)*CONVD + ch]), acc);
    }
    float v = siluf(acc);
    if (ci<64) X[l][ci] = v; else Bs[l][ci-64] = v;
  }
  __syncthreads();
  // states[p][n] = sum_l B[l][n]*wdec[l]*dt[l]*x[l][p]
  {
    const int n = tid & 15, pg = tid >> 4;
    const int p0 = pg<<2;
    float a0=0.f,a1=0.f,a2=0.f,a3=0.f;
    for (int l=0;l<64;l++){
      float bw = Bs[l][n]*wdec[l]*dts[l];
      float4 x4 = *(const float4*)&X[l][p0];
      a0 = fmaf(bw, x4.x, a0); a1 = fmaf(bw, x4.y, a1);
      a2 = fmaf(bw, x4.z, a2); a3 = fmaf(bw, x4.w, a3);
    }
    size_t base = ((size_t)bx<<10);
    states_g[base + (size_t)(p0+0)*16 + n] = a0;
    states_g[base + (size_t)(p0+1)*16 + n] = a1;
    states_g[base + (size_t)(p0+2)*16 + n] = a2;
    states_g[base + (size_t)(p0+3)*16 + n] = a3;
  }
}

// ---------------- inter-chunk state scan (in place) ----------------
__global__ __launch_bounds__(256) void scan_kernel(float* __restrict__ states,
  const float* __restrict__ atot)
{
  int gid = blockIdx.x*256 + threadIdx.x;   // BG*4096
  int inner = gid & 1023;
  int h = (gid>>10)&3;
  int bl = gid>>12;
  float S = 0.0f;
  for (int c=0;c<NCH;c++){
    int bx = ((bl*NCH + c)<<2) + h;
    size_t idx = ((size_t)bx<<10) + inner;
    float tmp = states[idx];
    states[idx] = S;
    S = __expf(atot[bx])*S + tmp;
  }
}

// ---------------- SSD back: conv(x,B,C)+silu, S, Ydiag+Yoff+D, gate, ssq ----------------
__global__ __launch_bounds__(256) void ssd_back(
  const unsigned short* __restrict__ xraw, const unsigned short* __restrict__ zb,
  const float* __restrict__ dtsp, const float* __restrict__ acs_g,
  const float* __restrict__ states, const float* __restrict__ Dp,
  const float* __restrict__ cw, const float* __restrict__ cb,
  unsigned short* __restrict__ yf, float* __restrict__ ssqp)
{
  __shared__ float X[64][68], Ss[64][68];
  __shared__ float Bs[64][17], Cs[64][17];
  __shared__ float Stt[16][68];
  __shared__ float part[64][17];
  __shared__ float acs_s[64], dts[64];
  const int bx = blockIdx.x;
  const int h = bx & 3, c = (bx>>2)&63, bl = bx>>8;
  const int tid = threadIdx.x;
  const int tokbase = (bl<<12) + (c<<6);

  if (tid < 64) {
    dts[tid]   = dtsp[(size_t)(tokbase+tid)*NHEADS + h];
    acs_s[tid] = acs_g[(size_t)bx*64 + tid];
  }
  // conv+silu: x-slice 64 + B 16 + C 16
  #pragma unroll
  for (int i=0;i<24;i++){
    int e = tid + (i<<8);
    int l = e/96, ci = e - l*96;
    int ch = (ci<64) ? (h<<6)+ci : ((ci<80) ? 256+(ci-64) : 272+(ci-80));
    float acc = cb[ch];
    #pragma unroll
    for (int k=0;k<4;k++){
      int t = (c<<6)+l-3+k;
      if (t >= 0) acc = fmaf(cw[ch*4+k], bf2f(xraw[(size_t)((bl<<12)+t)*CONVD + ch]), acc);
    }
    float v = siluf(acc);
    if (ci<64) X[l][ci] = v;
    else if (ci<80) Bs[l][ci-64] = v;
    else Cs[l][ci-80] = v;
  }
  // prior states -> transposed LDS
  #pragma unroll
  for (int i=0;i<4;i++){
    int e = tid + (i<<8);
    int p = e>>4, n = e&15;
    Stt[n][p] = states[((size_t)bx<<10) + e];
  }
  __syncthreads();
  // Ss[s][l] = exp(acs[l]-acs[s]) * dt[s] * (C[l]·B[s])   (s<=l)
  {
    const int l = tid & 63, sr = tid >> 6;
    float cv[16];
    #pragma unroll
    for (int n=0;n<16;n++) cv[n] = Cs[l][n];
    const float al = acs_s[l];
    #pragma unroll
    for (int i=0;i<16;i++){
      int s = sr*16 + i;
      float v = 0.0f;
      if (s <= l){
        float dot = 0.f;
        #pragma unroll
        for (int n=0;n<16;n++) dot = fmaf(cv[n], Bs[s][n], dot);
        v = __expf(al - acs_s[s]) * dts[s] * dot;
      }
      Ss[s][l] = v;
    }
  }
  __syncthreads();
  // Y = Ss^T·X + exp(acs)·C·St + D·x ; gate; ssq
  {
    const int lt = tid>>4, pt = tid&15;
    const int l0 = lt<<2, p0 = pt<<2;
    float acc[4][4] = {};
    for (int s=0;s<64;s++){
      float4 x4 = *(const float4*)&X[s][p0];
      float4 s4 = *(const float4*)&Ss[s][l0];
      float sv[4] = {s4.x, s4.y, s4.z, s4.w};
      #pragma unroll
      for (int i=0;i<4;i++){
        acc[i][0] = fmaf(sv[i], x4.x, acc[i][0]);
        acc[i][1] = fmaf(sv[i], x4.y, acc[i][1]);
        acc[i][2] = fmaf(sv[i], x4.z, acc[i][2]);
        acc[i][3] = fmaf(sv[i], x4.w, acc[i][3]);
      }
    }
    float off[4][4] = {};
    #pragma unroll
    for (int n=0;n<16;n++){
      float4 st4 = *(const float4*)&Stt[n][p0];
      float cv2[4];
      #pragma unroll
      for (int i=0;i<4;i++) cv2[i] = Cs[l0+i][n];
      #pragma unroll
      for (int i=0;i<4;i++){
        off[i][0] = fmaf(cv2[i], st4.x, off[i][0]);
        off[i][1] = fmaf(cv2[i], st4.y, off[i][1]);
        off[i][2] = fmaf(cv2[i], st4.z, off[i][2]);
        off[i][3] = fmaf(cv2[i], st4.w, off[i][3]);
      }
    }
    const float Dh = Dp[h];
    #pragma unroll
    for (int i=0;i<4;i++){
      int l = l0 + i;
      float eal = __expf(acs_s[l]);
      size_t idx = (size_t)(tokbase+l)*DIN + (h<<6) + p0;
      u16x4 z4 = *(const u16x4*)&zb[idx];
      u16x4 o4;
      float ps = 0.f;
      #pragma unroll
      for (int j=0;j<4;j++){
        float y = acc[i][j] + eal*off[i][j] + Dh*X[l][p0+j];
        float zv = bf2f(z4[j]);
        float yv = y * zv * sigm(zv);
        o4[j] = f2bf(yv);
        ps = fmaf(yv, yv, ps);
      }
      *(u16x4*)&yf[idx] = o4;
      part[l][pt] = ps;
      __syncthreads();  // note: executed uniformly? no -- see below
    }
  }
  // NOTE: the __syncthreads above inside the unrolled loop is uniform across
  // all 256 threads (loop bounds are compile-time), so it is safe, but we
  // only need one barrier before the reduction. The three extra barriers are
  // harmless ordering points; part[l][pt] is rewritten per i -- WRONG.
  // (restructured below to avoid overwrite; see part2 accumulation)
}

// Corrected ssd_back reduction: accumulate 4 partials per thread into part once.
// (The kernel above is replaced by this one; kept single definition.)
__global__ __launch_bounds__(256) void ssd_back2(
  const unsigned short* __restrict__ xraw, const unsigned short* __restrict__ zb,
  const float* __restrict__ dtsp, const float* __restrict__ acs_g,
  const float* __restrict__ states, const float* __restrict__ Dp,
  const float* __restrict__ cw, const float* __restrict__ cb,
  unsigned short* __restrict__ yf, float* __restrict__ ssqp)
{
  __shared__ float X[64][68], Ss[64][68];
  __shared__ float Bs[64][17], Cs[64][17];
  __shared__ float Stt[16][68];
  __shared__ float part[64][17];
  __shared__ float acs_s[64], dts[64];
  const int bx = blockIdx.x;
  const int h = bx & 3, c = (bx>>2)&63, bl = bx>>8;
  const int tid = threadIdx.x;
  const int tokbase = (bl<<12) + (c<<6);

  if (tid < 64) {
    dts[tid]   = dtsp[(size_t)(tokbase+tid)*NHEADS + h];
    acs_s[tid] = acs_g[(size_t)bx*64 + tid];
  }
  #pragma unroll
  for (int i=0;i<24;i++){
    int e = tid + (i<<8);
    int l = e/96, ci = e - l*96;
    int ch = (ci<64) ? (h<<6)+ci : ((ci<80) ? 256+(ci-64) : 272+(ci-80));
    float acc = cb[ch];
    #pragma unroll
    for (int k=0;k<4;k++){
      int t = (c<<6)+l-3+k;
      if (t >= 0) acc = fmaf(cw[ch*4+k], bf2f(xraw[(size_t)((bl<<12)+t)*CONVD + ch]), acc);
    }
    float v = siluf(acc);
    if (ci<64) X[l][ci] = v;
    else if (ci<80) Bs[l][ci-64] = v;
    else Cs[l][ci-80] = v;
  }
  #pragma unroll
  for (int i=0;i<4;i++){
    int e = tid + (i<<8);
    int p = e>>4, n = e&15;
    Stt[n][p] = states[((size_t)bx<<10) + e];
  }
  __syncthreads();
  {
    const int l = tid & 63, sr = tid >> 6;
    float cv[16];
    #pragma unroll
    for (int n=0;n<16;n++) cv[n] = Cs[l][n];
    const float al = acs_s[l];
    #pragma unroll
    for (int i=0;i<16;i++){
      int s = sr*16 + i;
      float v = 0.0f;
      if (s <= l){
        float dot = 0.f;
        #pragma unroll
        for (int n=0;n<16;n++) dot = fmaf(cv[n], Bs[s][n], dot);
        v = __expf(al - acs_s[s]) * dts[s] * dot;
      }
      Ss[s][l] = v;
    }
  }
  __syncthreads();
  {
    const int lt = tid>>4, pt = tid&15;
    const int l0 = lt<<2, p0 = pt<<2;
    float acc[4][4] = {};
    for (int s=0;s<64;s++){
      float4 x4 = *(const float4*)&X[s][p0];
      float4 s4 = *(const float4*)&Ss[s][l0];
      float sv[4] = {s4.x, s4.y, s4.z, s4.w};
      #pragma unroll
      for (int i=0;i<4;i++){
        acc[i][0] = fmaf(sv[i], x4.x, acc[i][0]);
        acc[i][1] = fmaf(sv[i], x4.y, acc[i][1]);
        acc[i][2] = fmaf(sv[i], x4.z, acc[i][2]);
        acc[i][3] = fmaf(sv[i], x4.w, acc[i][3]);
      }
    }
    float off[4][4] = {};
    #pragma unroll
    for (int n=0;n<16;n++){
      float4 st4 = *(const float4*)&Stt[n][p0];
      float cv2[4];
      #pragma unroll
      for (int i=0;i<4;i++) cv2[i] = Cs[l0+i][n];
      #pragma unroll
      for (int i=0;i<4;i++){
        off[i][0] = fmaf(cv2[i], st4.x, off[i][0]);
        off[i][1] = fmaf(cv2[i], st4.y, off[i][1]);
        off[i][2] = fmaf(cv2[i], st4.z, off[i][2]);
        off[i][3] = fmaf(cv2[i], st4.w, off[i][3]);
      }
    }
    const float Dh = Dp[h];
    #pragma unroll
    for (int i=0;i<4;i++){
      int l = l0 + i;
      float eal = __expf(acs_s[l]);
      size_t idx = (size_t)(tokbase+l)*DIN + (h<<6) + p0;
      u16x4 z4 = *(const u16x4*)&zb[idx];
      u16x4 o4;
      float ps = 0.f;
      #pragma unroll
      for (int j=0;j<4;j++){
        float y = acc[i][j] + eal*off[i][j] + Dh*X[l][p0+j];
        float zv = bf2f(z4[j]);
        float yv = y * zv * sigm(zv);
        o4[j] = f2bf(yv);
        ps = fmaf(yv, yv, ps);
      }
      *(u16x4*)&yf[idx] = o4;
      part[l][pt] = ps;   // each (l, pt) written by exactly one thread (l = l0+i unique per lt)
    }
  }
  __syncthreads();
  if (tid < 64){
    float s = 0.f;
    #pragma unroll
    for (int q=0;q<16;q++) s += part[tid][q];
    ssqp[(size_t)(tokbase+tid)*NHEADS + h] = s;
  }
}

// ---------------- sample = lm + noise*exp(0.5*lv) ----------------
__global__ __launch_bounds__(256) void sample_kernel(const float* __restrict__ lm,
  const float* __restrict__ lv, const float* __restrict__ nz, float* __restrict__ sp)
{
  int gid = blockIdx.x*256 + threadIdx.x;
  sp[gid] = fmaf(nz[gid], expf(0.5f*lv[gid]), lm[gid]);
}

// ---------------- gate + pred (fused is bf16) ----------------
__global__ __launch_bounds__(256) void gatepred_kernel(
  const unsigned short* __restrict__ fused, const float* __restrict__ sample,
  const float* __restrict__ gw, const float* __restrict__ gb,
  const float* __restrict__ ow, const float* __restrict__ ob,
  const float* __restrict__ rg, float* __restrict__ pred)
{
  __shared__ float gws[128][65];
  __shared__ float gbs[128], ows[128];
  const int tid = threadIdx.x;
  #pragma unroll
  for (int i=0;i<32;i++){ int e = tid + (i<<8); gws[e>>6][e&63] = gw[e]; }
  if (tid < 128){ gbs[tid] = gb[tid]; ows[tid] = ow[tid]; }
  __syncthreads();
  const int wave = tid>>6, lane = tid&63;
  const float ob0 = ob[0];
  for (int it=0; it<16; it++){
    int m = blockIdx.x*64 + wave*16 + it;
    float sv = sample[(size_t)m*LAT + lane];
    float acc0 = gbs[lane], acc1 = gbs[lane+64];
    #pragma unroll
    for (int k=0;k<64;k++){
      float sk = __shfl(sv, k);
      acc0 = fmaf(sk, gws[lane][k], acc0);
      acc1 = fmaf(sk, gws[lane+64][k], acc1);
    }
    float f0 = bf2f(fused[(size_t)m*128 + lane]);
    float f1 = bf2f(fused[(size_t)m*128 + 64 + lane]);
    float cval = f0*sigm(acc0)*ows[lane] + f1*sigm(acc1)*ows[lane+64];
    #pragma unroll
    for (int off=32; off; off>>=1) cval += __shfl_xor(cval, off);
    if (lane==0) pred[m] = (cval + ob0) * sigm(rg[m & 4095]);
  }
}

extern "C" void kernel_launch(void* const* d_in, const int* in_sizes, int n_in,
                              void* d_out, int out_size, void* d_ws, size_t ws_size,
                              hipStream_t stream)
{
  const float* expr      = (const float*)d_in[0];
  const float* noise     = (const float*)d_in[1];
  const float* expr_w    = (const float*)d_in[2];
  const float* expr_b    = (const float*)d_in[3];
  const float* in_proj_w = (const float*)d_in[4];
  const float* conv_w    = (const float*)d_in[5];
  const float* conv_b    = (const float*)d_in[6];
  const float* dt_bias   = (const float*)d_in[7];
  const float* A_log     = (const float*)d_in[8];
  const float* D_par     = (const float*)d_in[9];
  const float* norm_w    = (const float*)d_in[10];
  const float* out_proj_w= (const float*)d_in[11];
  const float* fusion_w  = (const float*)d_in[12];
  const float* fusion_b  = (const float*)d_in[13];
  const float* lm_w      = (const float*)d_in[14];
  const float* lm_b      = (const float*)d_in[15];
  const float* lv_w      = (const float*)d_in[16];
  const float* lv_b      = (const float*)d_in[17];
  const float* gate_w    = (const float*)d_in[18];
  const float* gate_b    = (const float*)d_in[19];
  const float* outp_w    = (const float*)d_in[20];
  const float* outp_b    = (const float*)d_in[21];
  const float* reg_gate  = (const float*)d_in[22];

  const size_t WBYTES = 921600;
  int BG = 0;
  const int cands[5] = {16, 8, 4, 2, 1};
  for (int ci = 0; ci < 5; ci++) {
    int c2 = cands[ci];
    size_t MGc = (size_t)c2 * LSEQ;
    size_t need = WBYTES + MGc*2416 + (size_t)c2*1024 + 256;
    if (need <= ws_size) { BG = c2; break; }
  }
  if (!BG) return;
  const size_t MG = (size_t)BG * LSEQ;

  unsigned short* wip = (unsigned short*)d_ws;      // 4*548*128
  unsigned short* wop = wip + 280576;               // 4*128*256 (nw folded)
  unsigned short* wfu = wop + 131072;               // 128*256
  unsigned short* wlm = wfu + 32768;                // 64*128
  unsigned short* wlv = wlm + 8192;                 // 64*128
  float* dtsp  = (float*)((char*)d_ws + WBYTES);    // MG*4
  float* acs   = dtsp + MG*4;                       // MG*4
  float* atot  = acs  + MG*4;                       // BG*256
  float* states= atot + (size_t)BG*256;             // MG*64
  float* ssqp  = states + MG*64;                    // MG*4
  unsigned short* zb    = (unsigned short*)(ssqp + MG*4);   // MG*256
  unsigned short* xrawb = zb    + MG*256;           // MG*288
  unsigned short* actA  = xrawb + MG*288;           // MG*128
  unsigned short* actB  = actA  + MG*128;           // MG*128
  unsigned short* yfb   = actB  + MG*128;           // MG*256
  unsigned short* fusedbf = yfb;                    // alias: yf dead after layers

  float* out_pred_g = (float*)d_out;
  float* out_lm_g   = out_pred_g + (size_t)16*LSEQ;
  float* out_lv_g   = out_lm_g   + (size_t)16*LSEQ*LAT;
  float* out_samp_g = out_lv_g   + (size_t)16*LSEQ*LAT;

  cvt_kernel<<<(280576+255)/256, 256, 0, stream>>>(in_proj_w, wip, 280576);
  cvt_nw_kernel<<<131072/256,    256, 0, stream>>>(out_proj_w, norm_w, wop, 131072);
  cvt_kernel<<<32768/256,        256, 0, stream>>>(fusion_w, wfu, 32768);
  cvt_kernel<<<8192/256,         256, 0, stream>>>(lm_w, wlm, 8192);
  cvt_kernel<<<8192/256,         256, 0, stream>>>(lv_w, wlv, 8192);

  for (int b0 = 0; b0 < 16; b0 += BG) {
    float* out_pred = out_pred_g + (size_t)b0*LSEQ;
    float* out_lm   = out_lm_g   + (size_t)b0*LSEQ*LAT;
    float* out_lv   = out_lv_g   + (size_t)b0*LSEQ*LAT;
    float* out_samp = out_samp_g + (size_t)b0*LSEQ*LAT;
    const float* nz = noise      + (size_t)b0*LSEQ*LAT;

    embed_kernel<<<(MG*128)/256, 256, 0, stream>>>(expr + (size_t)b0*LSEQ, expr_w, expr_b, actA, actB);

    for (int li = 0; li < 4; li++) {
      unsigned short* u = (li < 2) ? actA : actB;
      const unsigned short* Wi = wip + (size_t)li*DPROJ*HMOD;
      const unsigned short* Wo = wop + (size_t)li*HMOD*DIN;
      const float* cw  = conv_w + (size_t)li*CONVD*4;
      const float* cb  = conv_b + (size_t)li*CONVD;
      const float* dtb = dt_bias + (size_t)li*NHEADS;
      const float* Al  = A_log + (size_t)li*NHEADS;
      const float* Dl  = D_par + (size_t)li*NHEADS;

      gemm2<128,3,1><<<dim3(MG/128, 3), 256, 0, stream>>>(u, nullptr, Wi, dtb, nullptr, zb, xrawb, dtsp, DPROJ, 0);
      ssd_front<<<BG*256, 256, 0, stream>>>(xrawb, dtsp, Al, cw, cb, states, acs, atot);
      scan_kernel<<<(BG*LSEQ)/256, 256, 0, stream>>>(states, atot);
      ssd_back2<<<BG*256, 256, 0, stream>>>(xrawb, zb, dtsp, acs, states, Dl, cw, cb, yfb, ssqp);
      gemm2<256,1,4><<<dim3(MG/128, 2), 256, 0, stream>>>(yfb, nullptr, Wo, nullptr, ssqp, u, nullptr, nullptr, HMOD, HMOD);
    }

    gemm2<256,1,2><<<dim3(MG/128, 2), 256, 0, stream>>>(actA, actB, wfu, fusion_b, nullptr, fusedbf, nullptr, nullptr, HMOD, HMOD);
    gemm2<128,1,3><<<dim3(MG/128, 1), 256, 0, stream>>>(fusedbf, nullptr, wlm, lm_b, nullptr, nullptr, nullptr, out_lm, LAT, LAT);
    gemm2<128,1,3><<<dim3(MG/128, 1), 256, 0, stream>>>(fusedbf, nullptr, wlv, lv_b, nullptr, nullptr, nullptr, out_lv, LAT, LAT);
    sample_kernel<<<(MG*LAT)/256, 256, 0, stream>>>(out_lm, out_lv, nz, out_samp);
    gatepred_kernel<<<MG/64, 256, 0, stream>>>(fusedbf, out_samp, gate_w, gate_b, outp_w, outp_b, reg_gate, out_pred);
  }
}

// Round 5
// 932.414 us; speedup vs baseline: 3.7418x; 1.2628x over previous
//
#include <hip/hip_runtime.h>
#include <math.h>

#define HMOD 128
#define DIN 256
#define NHEADS 4
#define HD 64
#define DSTATE 16
#define NCH 64
#define CONVD 288
#define DPROJ 548
#define LAT 64
#define LSEQ 4096

typedef __attribute__((ext_vector_type(8))) short bf16x8;
typedef __attribute__((ext_vector_type(4))) float f32x4;
typedef __attribute__((ext_vector_type(4))) unsigned short u16x4;

__device__ __forceinline__ float sigm(float x){ return 1.0f/(1.0f+__expf(-x)); }
__device__ __forceinline__ float siluf(float x){ return x/(1.0f+__expf(-x)); }
__device__ __forceinline__ float softplusf(float x){ return (x>20.0f)? x : log1pf(expf(x)); }
__device__ __forceinline__ float geluf(float x){ return 0.5f*x*(1.0f+erff(x*0.70710678118654752440f)); }
__device__ __forceinline__ unsigned short f2bf(float x){
  unsigned int u = __float_as_uint(x);
  return (unsigned short)((u + 0x7FFFu + ((u>>16)&1u)) >> 16);
}
__device__ __forceinline__ float bf2f(unsigned short h){
  return __uint_as_float(((unsigned int)h)<<16);
}

// ---------------- weight conversion ----------------
__global__ __launch_bounds__(256) void cvt_kernel(const float* __restrict__ in,
  unsigned short* __restrict__ out, int n)
{
  int i = blockIdx.x*256 + threadIdx.x;
  if (i < n) out[i] = f2bf(in[i]);
}
__global__ __launch_bounds__(256) void cvt_nw_kernel(const float* __restrict__ in,
  const float* __restrict__ nw, unsigned short* __restrict__ out, int n)
{
  int i = blockIdx.x*256 + threadIdx.x;
  if (i < n){
    int k = i & 255;
    int li = i >> 15;
    out[i] = f2bf(in[i]*nw[li*256 + k]);
  }
}

// ---------------- embedding ----------------
__global__ __launch_bounds__(256) void embed_kernel(const float* __restrict__ expr,
    const float* __restrict__ ew, const float* __restrict__ eb,
    unsigned short* __restrict__ actA, unsigned short* __restrict__ actB)
{
  int gid = blockIdx.x*256 + threadIdx.x;
  int m = gid >> 7, hh = gid & 127;
  int bl = m >> 12, g = m & 4095;
  unsigned short v = f2bf(expr[m]*ew[hh] + eb[hh]);
  actA[gid] = v;
  actB[(size_t)(((bl<<12) | (4095-g))<<7) + hh] = v;
}

// ---------------- MFMA GEMM: C[M,N] = A[M,K] @ W[N,K]^T ----------------
template<int KDIM, int NT, int EPI>
__global__ __launch_bounds__(256) void gemm2(
    const unsigned short* __restrict__ A,
    const unsigned short* __restrict__ A2,
    const unsigned short* __restrict__ Wb,
    const float* __restrict__ bias,
    const float* __restrict__ ssqp,
    unsigned short* __restrict__ ob1,
    unsigned short* __restrict__ ob2,
    float* __restrict__ of1,
    int N, int ldc)
{
  __shared__ unsigned short Ws[64*(KDIM+8)];
  const int tid = threadIdx.x;
  const int m0 = blockIdx.x<<7;
  const int wid = tid>>6, lane = tid&63;
  const int la = lane&15, kq = lane>>4;
  const int mw = m0 + wid*32;

  bf16x8 af[KDIM/32][2];
  #pragma unroll
  for (int ki=0; ki<KDIM/32; ki++){
    int k = ki*32 + kq*8;
    #pragma unroll
    for (int mf=0; mf<2; mf++){
      int row = mw + mf*16 + la;
      const unsigned short* src;
      if (EPI==2){
        if (k < 128) src = A + (size_t)row*128 + k;
        else { int bl2=row>>12, t=row&4095; src = A2 + (size_t)(((bl2<<12)|(4095-t)))*128 + (k-128); }
      } else {
        src = A + (size_t)row*KDIM + k;
      }
      af[ki][mf] = *(const bf16x8*)src;
    }
  }
  float scv[2][4];
  if (EPI==4){
    #pragma unroll
    for (int mf=0; mf<2; mf++)
      #pragma unroll
      for (int r=0; r<4; r++){
        int m = mw + mf*16 + kq*4 + r;
        float s = ssqp[m*4]+ssqp[m*4+1]+ssqp[m*4+2]+ssqp[m*4+3];
        scv[mf][r] = rsqrtf(s*(1.0f/256.0f) + 1e-5f);
      }
  }

  const int KD8 = KDIM/8;
  for (int nt=0; nt<NT; nt++){
    int n0 = (blockIdx.y*NT + nt)<<6;
    if (nt) __syncthreads();
    for (int ci = tid; ci < 64*KD8; ci += 256){
      int row = ci/KD8, kc = (ci - row*KD8)*8;
      int n = n0 + row;
      bf16x8 v = {0,0,0,0,0,0,0,0};
      if (n < N) v = *(const bf16x8*)&Wb[(size_t)n*KDIM + kc];
      *(bf16x8*)&Ws[row*(KDIM+8) + kc] = v;
    }
    __syncthreads();
    f32x4 acc[2][4] = {};
    #pragma unroll
    for (int ki=0; ki<KDIM/32; ki++){
      #pragma unroll
      for (int nf=0; nf<4; nf++){
        bf16x8 bfr = *(const bf16x8*)&Ws[(nf*16 + la)*(KDIM+8) + ki*32 + kq*8];
        #pragma unroll
        for (int mf=0; mf<2; mf++)
          acc[mf][nf] = __builtin_amdgcn_mfma_f32_16x16x32_bf16(af[ki][mf], bfr, acc[mf][nf], 0,0,0);
      }
    }
    #pragma unroll
    for (int mf=0; mf<2; mf++){
      #pragma unroll
      for (int nf=0; nf<4; nf++){
        #pragma unroll
        for (int r=0; r<4; r++){
          int m = mw + mf*16 + kq*4 + r;
          int n = n0 + nf*16 + la;
          float v = acc[mf][nf][r];
          if (EPI==1){
            if (n < DIN)            ob1[(size_t)m*DIN + n] = f2bf(v);
            else if (n < DIN+CONVD) ob2[(size_t)m*CONVD + (n-DIN)] = f2bf(v);
            else if (n < DPROJ)     of1[(size_t)m*NHEADS + (n-DIN-CONVD)] = softplusf(v + bias[n-DIN-CONVD]);
          } else if (EPI==2){
            if (n < N) ob1[(size_t)m*ldc + n] = f2bf(geluf(v + bias[n]));
          } else if (EPI==3){
            if (n < N) of1[(size_t)m*ldc + n] = v + bias[n];
          } else if (EPI==4){
            if (n < N) ob1[(size_t)m*ldc + n] = f2bf(v*scv[mf][r]);
          }
        }
      }
    }
  }
}

// ---------------- SSD front: conv+silu, A-cumsum, chunk states (MFMA) ----------------
__global__ __launch_bounds__(256) void ssd_front(
  const unsigned short* __restrict__ xraw, const float* __restrict__ dtsp,
  const float* __restrict__ Alog,
  const float* __restrict__ cw, const float* __restrict__ cb,
  float* __restrict__ states_g, float* __restrict__ acs_g, float* __restrict__ atot_g)
{
  __shared__ unsigned short Xt[64][72];    // Xt[p][l]
  __shared__ unsigned short Bwt[16][72];   // Bwt[n][l] = B*wdec*dt
  __shared__ float acs_s[64], dts[64], wdec[64];
  const int bx = blockIdx.x;               // bl*256 + c*4 + h
  const int h = bx & 3, c = (bx>>2)&63, bl = bx>>8;
  const int tid = threadIdx.x;
  const int tokbase = (bl<<12) + (c<<6);

  if (tid < 64) {
    float dt = dtsp[(size_t)(tokbase+tid)*NHEADS + h];
    dts[tid] = dt;
    float xsc = -__expf(Alog[h]) * dt;
    #pragma unroll
    for (int off=1; off<64; off<<=1){ float v = __shfl_up(xsc, off); if (tid >= off) xsc += v; }
    acs_s[tid] = xsc;
    acs_g[(size_t)bx*64 + tid] = xsc;
  }
  __syncthreads();
  const float atotv = acs_s[63];
  if (tid < 64) {
    wdec[tid] = __expf(atotv - acs_s[tid]);
    if (tid==0) atot_g[bx] = atotv;
  }
  __syncthreads();
  // conv+silu: x (64ch) + B (16ch)
  #pragma unroll
  for (int i=0;i<20;i++){
    int e = tid + (i<<8);
    int l = e/80, ci = e - l*80;
    int ch = (ci<64) ? (h<<6)+ci : 256+(ci-64);
    float acc = cb[ch];
    #pragma unroll
    for (int k=0;k<4;k++){
      int t = (c<<6)+l-3+k;
      if (t >= 0) acc = fmaf(cw[ch*4+k], bf2f(xraw[(size_t)((bl<<12)+t)*CONVD + ch]), acc);
    }
    float v = siluf(acc);
    if (ci<64) Xt[ci][l] = f2bf(v);
    else Bwt[ci-64][l] = f2bf(v*wdec[l]*dts[l]);
  }
  __syncthreads();
  // states[p][n] = sum_l Xt[p][l]*Bwt[n][l] via MFMA (M=64 p, N=16, K=64)
  const int wid = tid>>6, lane = tid&63;
  const int la = lane&15, kq = lane>>4;
  f32x4 acc = {0.f,0.f,0.f,0.f};
  #pragma unroll
  for (int kt=0; kt<2; kt++){
    bf16x8 a = *(const bf16x8*)&Xt[wid*16+la][kt*32+kq*8];
    bf16x8 b = *(const bf16x8*)&Bwt[la][kt*32+kq*8];
    acc = __builtin_amdgcn_mfma_f32_16x16x32_bf16(a, b, acc, 0,0,0);
  }
  size_t base = (size_t)bx<<10;
  #pragma unroll
  for (int r=0;r<4;r++){
    int p = wid*16 + kq*4 + r;
    states_g[base + (size_t)p*16 + la] = acc[r];
  }
}

// ---------------- inter-chunk state scan (in place) ----------------
__global__ __launch_bounds__(256) void scan_kernel(float* __restrict__ states,
  const float* __restrict__ atot)
{
  int gid = blockIdx.x*256 + threadIdx.x;   // BG*4096
  int inner = gid & 1023;
  int h = (gid>>10)&3;
  int bl = gid>>12;
  float S = 0.0f;
  for (int c=0;c<NCH;c++){
    int bx = ((bl*NCH + c)<<2) + h;
    size_t idx = ((size_t)bx<<10) + inner;
    float tmp = states[idx];
    states[idx] = S;
    S = __expf(atot[bx])*S + tmp;
  }
}

// ---------------- SSD back: conv, S (MFMA), Y (MFMA), gate, ssq ----------------
__global__ __launch_bounds__(256) void ssd_back(
  const unsigned short* __restrict__ xraw, const unsigned short* __restrict__ zb,
  const float* __restrict__ dtsp, const float* __restrict__ acs_g,
  const float* __restrict__ states, const float* __restrict__ Dp,
  const float* __restrict__ cw, const float* __restrict__ cb,
  unsigned short* __restrict__ yf, float* __restrict__ ssqp)
{
  __shared__ unsigned short Xt[64][72];   // Xt[p][l]
  __shared__ unsigned short Sb[64][72];   // Sb[l][s] (masked, * dt[s] * exp)
  __shared__ unsigned short Cp[64][40];   // C[l][n], k padded to 32 with zeros
  __shared__ unsigned short Bp[64][40];   // B[s][n], padded
  __shared__ unsigned short Sp[64][40];   // prior states[p][n], padded
  __shared__ float acs_s[64], dts[64];
  const int bx = blockIdx.x;
  const int h = bx & 3, c = (bx>>2)&63, bl = bx>>8;
  const int tid = threadIdx.x;
  const int tokbase = (bl<<12) + (c<<6);

  if (tid < 64) {
    dts[tid]   = dtsp[(size_t)(tokbase+tid)*NHEADS + h];
    acs_s[tid] = acs_g[(size_t)bx*64 + tid];
  }
  // zero the k=16..31 pad region of the three K-padded tiles
  for (int i = tid; i < 64*16; i += 256){
    int l = i>>4, k = 16 + (i&15);
    Cp[l][k] = 0; Bp[l][k] = 0; Sp[l][k] = 0;
  }
  // conv+silu: x (64) + B (16) + C (16)
  #pragma unroll
  for (int i=0;i<24;i++){
    int e = tid + (i<<8);
    int l = e/96, ci = e - l*96;
    int ch = (ci<64) ? (h<<6)+ci : ((ci<80) ? 256+(ci-64) : 272+(ci-80));
    float acc = cb[ch];
    #pragma unroll
    for (int k=0;k<4;k++){
      int t = (c<<6)+l-3+k;
      if (t >= 0) acc = fmaf(cw[ch*4+k], bf2f(xraw[(size_t)((bl<<12)+t)*CONVD + ch]), acc);
    }
    float v = siluf(acc);
    if (ci<64) Xt[ci][l] = f2bf(v);
    else if (ci<80) Bp[l][ci-64] = f2bf(v);
    else Cp[l][ci-80] = f2bf(v);
  }
  // prior chunk states -> bf16
  #pragma unroll
  for (int i=0;i<4;i++){
    int e = tid + (i<<8);
    int p = e>>4, n = e&15;
    Sp[p][n] = f2bf(states[((size_t)bx<<10) + e]);
  }
  __syncthreads();

  const int wid = tid>>6, lane = tid&63;
  const int la = lane&15, kq = lane>>4;
  const int L0 = wid*16;
  const f32x4 zero4 = {0.f,0.f,0.f,0.f};

  // CB = C·B^T (K=32 padded), then mask/scale -> Sb bf16
  {
    bf16x8 a = *(const bf16x8*)&Cp[L0+la][kq*8];
    f32x4 cbacc[4];
    #pragma unroll
    for (int nf=0; nf<4; nf++){
      bf16x8 b = *(const bf16x8*)&Bp[nf*16+la][kq*8];
      cbacc[nf] = __builtin_amdgcn_mfma_f32_16x16x32_bf16(a, b, zero4, 0,0,0);
    }
    #pragma unroll
    for (int nf=0; nf<4; nf++){
      #pragma unroll
      for (int r=0; r<4; r++){
        int l = L0 + kq*4 + r, s = nf*16 + la;
        float v = 0.f;
        if (s <= l) v = __expf(acs_s[l]-acs_s[s])*dts[s]*cbacc[nf][r];
        Sb[l][s] = f2bf(v);
      }
    }
  }
  // Y_off = C·Sp^T, scaled by exp(acs[l]) -> init accumulator
  f32x4 ya[4];
  {
    bf16x8 a = *(const bf16x8*)&Cp[L0+la][kq*8];
    #pragma unroll
    for (int nf=0; nf<4; nf++){
      bf16x8 b = *(const bf16x8*)&Sp[nf*16+la][kq*8];
      ya[nf] = __builtin_amdgcn_mfma_f32_16x16x32_bf16(a, b, zero4, 0,0,0);
    }
    float eal[4];
    #pragma unroll
    for (int r=0; r<4; r++) eal[r] = __expf(acs_s[L0 + kq*4 + r]);
    #pragma unroll
    for (int nf=0; nf<4; nf++)
      #pragma unroll
      for (int r=0; r<4; r++) ya[nf][r] *= eal[r];
  }
  __syncthreads();   // Sb fully written (also orders intra-wave write->fragment-read)
  // Y_diag += Sb·Xt^T (K=64)
  #pragma unroll
  for (int kt=0; kt<2; kt++){
    bf16x8 a = *(const bf16x8*)&Sb[L0+la][kt*32+kq*8];
    #pragma unroll
    for (int nf=0; nf<4; nf++){
      bf16x8 b = *(const bf16x8*)&Xt[nf*16+la][kt*32+kq*8];
      ya[nf] = __builtin_amdgcn_mfma_f32_16x16x32_bf16(a, b, ya[nf], 0,0,0);
    }
  }
  // epilogue: +D*x, z-gate, store yf, ssq
  const float Dh = Dp[h];
  float pssq[4] = {0.f,0.f,0.f,0.f};
  #pragma unroll
  for (int nf=0; nf<4; nf++){
    #pragma unroll
    for (int r=0; r<4; r++){
      int l = L0 + kq*4 + r, p = nf*16 + la;
      float y = ya[nf][r] + Dh*bf2f(Xt[p][l]);
      size_t idx = (size_t)(tokbase+l)*DIN + (h<<6) + p;
      float zv = bf2f(zb[idx]);
      float yv = y * zv * sigm(zv);
      yf[idx] = f2bf(yv);
      pssq[r] = fmaf(yv, yv, pssq[r]);
    }
  }
  #pragma unroll
  for (int r=0; r<4; r++){
    float s = pssq[r];
    s += __shfl_xor(s, 1); s += __shfl_xor(s, 2);
    s += __shfl_xor(s, 4); s += __shfl_xor(s, 8);
    if (la == 0){
      int l = L0 + kq*4 + r;
      ssqp[(size_t)(tokbase+l)*NHEADS + h] = s;
    }
  }
}

// ---------------- sample ----------------
__global__ __launch_bounds__(256) void sample_kernel(const float* __restrict__ lm,
  const float* __restrict__ lv, const float* __restrict__ nz, float* __restrict__ sp)
{
  int gid = blockIdx.x*256 + threadIdx.x;
  sp[gid] = fmaf(nz[gid], expf(0.5f*lv[gid]), lm[gid]);
}

// ---------------- gate + pred ----------------
__global__ __launch_bounds__(256) void gatepred_kernel(
  const unsigned short* __restrict__ fused, const float* __restrict__ sample,
  const float* __restrict__ gw, const float* __restrict__ gb,
  const float* __restrict__ ow, const float* __restrict__ ob,
  const float* __restrict__ rg, float* __restrict__ pred)
{
  __shared__ float gws[128][65];
  __shared__ float gbs[128], ows[128];
  const int tid = threadIdx.x;
  #pragma unroll
  for (int i=0;i<32;i++){ int e = tid + (i<<8); gws[e>>6][e&63] = gw[e]; }
  if (tid < 128){ gbs[tid] = gb[tid]; ows[tid] = ow[tid]; }
  __syncthreads();
  const int wave = tid>>6, lane = tid&63;
  const float ob0 = ob[0];
  for (int it=0; it<16; it++){
    int m = blockIdx.x*64 + wave*16 + it;
    float sv = sample[(size_t)m*LAT + lane];
    float acc0 = gbs[lane], acc1 = gbs[lane+64];
    #pragma unroll
    for (int k=0;k<64;k++){
      float sk = __shfl(sv, k);
      acc0 = fmaf(sk, gws[lane][k], acc0);
      acc1 = fmaf(sk, gws[lane+64][k], acc1);
    }
    float f0 = bf2f(fused[(size_t)m*128 + lane]);
    float f1 = bf2f(fused[(size_t)m*128 + 64 + lane]);
    float cval = f0*sigm(acc0)*ows[lane] + f1*sigm(acc1)*ows[lane+64];
    #pragma unroll
    for (int off=32; off; off>>=1) cval += __shfl_xor(cval, off);
    if (lane==0) pred[m] = (cval + ob0) * sigm(rg[m & 4095]);
  }
}

extern "C" void kernel_launch(void* const* d_in, const int* in_sizes, int n_in,
                              void* d_out, int out_size, void* d_ws, size_t ws_size,
                              hipStream_t stream)
{
  const float* expr      = (const float*)d_in[0];
  const float* noise     = (const float*)d_in[1];
  const float* expr_w    = (const float*)d_in[2];
  const float* expr_b    = (const float*)d_in[3];
  const float* in_proj_w = (const float*)d_in[4];
  const float* conv_w    = (const float*)d_in[5];
  const float* conv_b    = (const float*)d_in[6];
  const float* dt_bias   = (const float*)d_in[7];
  const float* A_log     = (const float*)d_in[8];
  const float* D_par     = (const float*)d_in[9];
  const float* norm_w    = (const float*)d_in[10];
  const float* out_proj_w= (const float*)d_in[11];
  const float* fusion_w  = (const float*)d_in[12];
  const float* fusion_b  = (const float*)d_in[13];
  const float* lm_w      = (const float*)d_in[14];
  const float* lm_b      = (const float*)d_in[15];
  const float* lv_w      = (const float*)d_in[16];
  const float* lv_b      = (const float*)d_in[17];
  const float* gate_w    = (const float*)d_in[18];
  const float* gate_b    = (const float*)d_in[19];
  const float* outp_w    = (const float*)d_in[20];
  const float* outp_b    = (const float*)d_in[21];
  const float* reg_gate  = (const float*)d_in[22];

  const size_t WBYTES = 921600;
  int BG = 0;
  const int cands[5] = {16, 8, 4, 2, 1};
  for (int ci = 0; ci < 5; ci++) {
    int c2 = cands[ci];
    size_t MGc = (size_t)c2 * LSEQ;
    size_t need = WBYTES + MGc*2416 + (size_t)c2*1024 + 256;
    if (need <= ws_size) { BG = c2; break; }
  }
  if (!BG) return;
  const size_t MG = (size_t)BG * LSEQ;

  unsigned short* wip = (unsigned short*)d_ws;
  unsigned short* wop = wip + 280576;
  unsigned short* wfu = wop + 131072;
  unsigned short* wlm = wfu + 32768;
  unsigned short* wlv = wlm + 8192;
  float* dtsp  = (float*)((char*)d_ws + WBYTES);
  float* acs   = dtsp + MG*4;
  float* atot  = acs  + MG*4;
  float* states= atot + (size_t)BG*256;
  float* ssqp  = states + MG*64;
  unsigned short* zb    = (unsigned short*)(ssqp + MG*4);
  unsigned short* xrawb = zb    + MG*256;
  unsigned short* actA  = xrawb + MG*288;
  unsigned short* actB  = actA  + MG*128;
  unsigned short* yfb   = actB  + MG*128;
  unsigned short* fusedbf = yfb;

  float* out_pred_g = (float*)d_out;
  float* out_lm_g   = out_pred_g + (size_t)16*LSEQ;
  float* out_lv_g   = out_lm_g   + (size_t)16*LSEQ*LAT;
  float* out_samp_g = out_lv_g   + (size_t)16*LSEQ*LAT;

  cvt_kernel<<<(280576+255)/256, 256, 0, stream>>>(in_proj_w, wip, 280576);
  cvt_nw_kernel<<<131072/256,    256, 0, stream>>>(out_proj_w, norm_w, wop, 131072);
  cvt_kernel<<<32768/256,        256, 0, stream>>>(fusion_w, wfu, 32768);
  cvt_kernel<<<8192/256,         256, 0, stream>>>(lm_w, wlm, 8192);
  cvt_kernel<<<8192/256,         256, 0, stream>>>(lv_w, wlv, 8192);

  for (int b0 = 0; b0 < 16; b0 += BG) {
    float* out_pred = out_pred_g + (size_t)b0*LSEQ;
    float* out_lm   = out_lm_g   + (size_t)b0*LSEQ*LAT;
    float* out_lv   = out_lv_g   + (size_t)b0*LSEQ*LAT;
    float* out_samp = out_samp_g + (size_t)b0*LSEQ*LAT;
    const float* nz = noise      + (size_t)b0*LSEQ*LAT;

    embed_kernel<<<(MG*128)/256, 256, 0, stream>>>(expr + (size_t)b0*LSEQ, expr_w, expr_b, actA, actB);

    for (int li = 0; li < 4; li++) {
      unsigned short* u = (li < 2) ? actA : actB;
      const unsigned short* Wi = wip + (size_t)li*DPROJ*HMOD;
      const unsigned short* Wo = wop + (size_t)li*HMOD*DIN;
      const float* cw  = conv_w + (size_t)li*CONVD*4;
      const float* cb  = conv_b + (size_t)li*CONVD;
      const float* dtb = dt_bias + (size_t)li*NHEADS;
      const float* Al  = A_log + (size_t)li*NHEADS;
      const float* Dl  = D_par + (size_t)li*NHEADS;

      gemm2<128,3,1><<<dim3(MG/128, 3), 256, 0, stream>>>(u, nullptr, Wi, dtb, nullptr, zb, xrawb, dtsp, DPROJ, 0);
      ssd_front<<<BG*256, 256, 0, stream>>>(xrawb, dtsp, Al, cw, cb, states, acs, atot);
      scan_kernel<<<(BG*LSEQ)/256, 256, 0, stream>>>(states, atot);
      ssd_back<<<BG*256, 256, 0, stream>>>(xrawb, zb, dtsp, acs, states, Dl, cw, cb, yfb, ssqp);
      gemm2<256,1,4><<<dim3(MG/128, 2), 256, 0, stream>>>(yfb, nullptr, Wo, nullptr, ssqp, u, nullptr, nullptr, HMOD, HMOD);
    }

    gemm2<256,1,2><<<dim3(MG/128, 2), 256, 0, stream>>>(actA, actB, wfu, fusion_b, nullptr, fusedbf, nullptr, nullptr, HMOD, HMOD);
    gemm2<128,1,3><<<dim3(MG/128, 1), 256, 0, stream>>>(fusedbf, nullptr, wlm, lm_b, nullptr, nullptr, nullptr, out_lm, LAT, LAT);
    gemm2<128,1,3><<<dim3(MG/128, 1), 256, 0, stream>>>(fusedbf, nullptr, wlv, lv_b, nullptr, nullptr, nullptr, out_lv, LAT, LAT);
    sample_kernel<<<(MG*LAT)/256, 256, 0, stream>>>(out_lm, out_lv, nz, out_samp);
    gatepred_kernel<<<MG/64, 256, 0, stream>>>(fusedbf, out_samp, gate_w, gate_b, outp_w, outp_b, reg_gate, out_pred);
  }
}